// Round 4
// baseline (209.019 us; speedup 1.0000x reference)
//
#include <hip/hip_runtime.h>

#define SEQ   2048
#define NBATCH 8
#define EMB   1024
#define HD    64
#define QKVSZ (NBATCH * SEQ * HD)   /* 1048576 elems per matrix */
#define WTSZ  (3 * HD * EMB)        /* 196608 */
#define PSLOT2 4224                 /* 64*64 O + 64 m + 64 l */

typedef __attribute__((ext_vector_type(8))) short bf16x8;
typedef __attribute__((ext_vector_type(4))) float f32x4;

__device__ inline unsigned short f2b(float f) {
  union { float f; unsigned int i; } u; u.f = f;
  unsigned int r = (u.i + 0x7FFFu + ((u.i >> 16) & 1u)) >> 16;  // RNE
  return (unsigned short)r;
}

// ---------------- W transpose -> K-blocked layout [kb][m][c][kd] ----------------
__global__ __launch_bounds__(256) void wtrans_kernel(const float* __restrict__ wq,
                                                     const float* __restrict__ wk,
                                                     const float* __restrict__ wv,
                                                     unsigned short* __restrict__ wt) {
  int i = blockIdx.x * 256 + threadIdx.x;       // 0 .. 196607
  int kb  = i / 12288;
  int rem = i - kb * 12288;
  int m   = rem >> 12;          // 0..2
  int c   = (rem >> 6) & 63;    // output col within head
  int kd  = rem & 63;           // k within block
  const float* src = (m == 0) ? wq : ((m == 1) ? wk : wv);
  int d = kb * 64 + kd;
  wt[i] = f2b(src[d * 64 + c]);
}

// ---------------- QKV projection (R3 proven, verbatim) ----------------
__global__ __launch_bounds__(256, 4) void qkv_proj_kernel(const float* __restrict__ emb,
                                                          const unsigned short* __restrict__ wt,
                                                          unsigned short* __restrict__ qkv) {
  __shared__ __align__(16) unsigned short Ab[2][32 * 64];   // 8 KB  (row stride 128B, swizzled)
  __shared__ __align__(16) unsigned short Wb[2][96 * 64];   // 24 KB (col stride 128B, swizzled)

  const int t    = threadIdx.x;
  const int wave = t >> 6;
  const int lane = t & 63;
  const int quad = lane >> 4;
  const int l16  = lane & 15;
  const int bx = blockIdx.x;
  const int rt = bx >> 1;          // row tile (32 rows)
  const int ch = bx & 1;           // col half (96 cols)
  const int wr = wave >> 1;        // row sub-tile (16 rows)
  const int wc = wave & 1;         // col sub (48 cols = 3 MFMA tiles)

  const float* aBase = emb + (size_t)rt * 32 * EMB;
  const unsigned short* wBase = wt + ch * 6144;   // col-half offset within each kb chunk

  f32x4 acc[3];
#pragma unroll
  for (int j = 0; j < 3; j++) acc[j] = (f32x4){0.f, 0.f, 0.f, 0.f};

  f32x4 pa[2];
  bf16x8 pw[3];

  // ---- prologue: load tile kb=0 into regs, stage to buf0 ----
#pragma unroll
  for (int j = 0; j < 2; j++) {
    int u = t + j * 256;
    pa[j] = *(const f32x4*)(aBase + (size_t)(u >> 4) * EMB + (u & 15) * 4);
  }
#pragma unroll
  for (int j = 0; j < 3; j++) {
    int u = t + j * 256;
    pw[j] = *(const bf16x8*)(wBase + u * 8);
  }
#pragma unroll
  for (int j = 0; j < 2; j++) {
    int u = t + j * 256;
    int row = u >> 4, kq = u & 15;
    unsigned int lo = (unsigned int)f2b(pa[j][0]) | ((unsigned int)f2b(pa[j][1]) << 16);
    unsigned int hi = (unsigned int)f2b(pa[j][2]) | ((unsigned int)f2b(pa[j][3]) << 16);
    uint2 pk; pk.x = lo; pk.y = hi;
    *(uint2*)((char*)&Ab[0][0] + row * 128 + ((kq * 8) ^ ((row & 7) << 4))) = pk;
  }
#pragma unroll
  for (int j = 0; j < 3; j++) {
    int u = t + j * 256;
    int coll = u >> 3, kd8 = u & 7;
    *(bf16x8*)((char*)&Wb[0][0] + coll * 128 + ((kd8 ^ (coll & 7)) << 4)) = pw[j];
  }
  __syncthreads();

  // ---- main loop over 16 K-steps ----
#pragma unroll 2
  for (int kb = 0; kb < 16; kb++) {
    const int cur = kb & 1;

    if (kb < 15) {
#pragma unroll
      for (int j = 0; j < 2; j++) {
        int u = t + j * 256;
        pa[j] = *(const f32x4*)(aBase + (size_t)(u >> 4) * EMB + (kb + 1) * 64 + (u & 15) * 4);
      }
#pragma unroll
      for (int j = 0; j < 3; j++) {
        int u = t + j * 256;
        pw[j] = *(const bf16x8*)(wBase + (kb + 1) * 12288 + u * 8);
      }
    }

    const int arow = wr * 16 + l16;
#pragma unroll
    for (int kh = 0; kh < 2; kh++) {
      bf16x8 af = *(const bf16x8*)((const char*)&Ab[cur][0] + arow * 128 +
                                   ((kh * 64 + quad * 16) ^ ((arow & 7) << 4)));
#pragma unroll
      for (int j = 0; j < 3; j++) {
        const int coll = (wc * 3 + j) * 16 + l16;
        bf16x8 wf = *(const bf16x8*)((const char*)&Wb[cur][0] + coll * 128 +
                                     ((kh * 64 + quad * 16) ^ ((coll & 7) << 4)));
        acc[j] = __builtin_amdgcn_mfma_f32_16x16x32_bf16(af, wf, acc[j], 0, 0, 0);
      }
    }

    if (kb < 15) {
      const int nb = cur ^ 1;
#pragma unroll
      for (int j = 0; j < 2; j++) {
        int u = t + j * 256;
        int row = u >> 4, kq = u & 15;
        unsigned int lo = (unsigned int)f2b(pa[j][0]) | ((unsigned int)f2b(pa[j][1]) << 16);
        unsigned int hi = (unsigned int)f2b(pa[j][2]) | ((unsigned int)f2b(pa[j][3]) << 16);
        uint2 pk; pk.x = lo; pk.y = hi;
        *(uint2*)((char*)&Ab[nb][0] + row * 128 + ((kq * 8) ^ ((row & 7) << 4))) = pk;
      }
#pragma unroll
      for (int j = 0; j < 3; j++) {
        int u = t + j * 256;
        int coll = u >> 3, kd8 = u & 7;
        *(bf16x8*)((char*)&Wb[nb][0] + coll * 128 + ((kd8 ^ (coll & 7)) << 4)) = pw[j];
      }
      __syncthreads();
    }
  }

  // ---- epilogue: Q,K natural stores ----
#pragma unroll
  for (int j = 0; j < 3; j++) {
    int gc = ch * 96 + (wc * 3 + j) * 16 + l16;
    if (gc < 128) {                               // uniform per (wave,j)
      int m  = gc >> 6, cm = gc & 63;
#pragma unroll
      for (int r = 0; r < 4; r++) {
        int row = rt * 32 + wr * 16 + quad * 4 + r;   // C/D: row = quad*4+reg, col = l16
        qkv[(size_t)m * QKVSZ + (size_t)row * HD + cm] = f2b(acc[j][r]);
      }
    }
  }

  // ---- epilogue: V -> LDS transpose -> vT[b][h][s] coalesced store ----
  if (ch == 1) {
    __syncthreads();                               // LDS free after last MFMA
    unsigned short* Vsh = (unsigned short*)&Ab[0][0];   // 64 h x 40 pitch = 5120 shorts
#pragma unroll
    for (int j = 0; j < 3; j++) {
      int gc = 96 + (wc * 3 + j) * 16 + l16;
      if (gc >= 128) {
        int h = gc - 128;
#pragma unroll
        for (int r = 0; r < 4; r++)
          Vsh[h * 40 + wr * 16 + quad * 4 + r] = f2b(acc[j][r]);
      }
    }
    __syncthreads();
    int h  = t >> 2;
    int sq = (t & 3) * 8;
    int row0 = rt * 32;
    int b    = row0 >> 11;
    int seq0 = row0 & 2047;
    bf16x8 vv = *(const bf16x8*)(Vsh + h * 40 + sq);
    *(bf16x8*)(qkv + 2 * (size_t)QKVSZ + ((size_t)(b * 64 + h)) * SEQ + seq0 + sq) = vv;
  }
}

// ---------------- Flash attention: 4 waves/block, 64 q-rows, 4-tile split-K chunks --------
// grid = (32 qblocks, 8 chunks, 8 batch). Block (B0,c) covers k-tiles [4c, min(4c+3,B0)];
// inactive chunks (c > B0/4) exit. All 4 waves share one staged K/V tile (double-buffered,
// ONE barrier per tile-step); diagonal tile == B0 for all 4 waves -> zero masked waste.
__global__ __launch_bounds__(256, 4) void attn_split(const unsigned short* __restrict__ qkv,
                                                     float* __restrict__ part,
                                                     float* __restrict__ out) {
  __shared__ __align__(16) unsigned short Kb[2][64 * 64];   // 2 x 8 KB, swizzled rows
  __shared__ __align__(16) unsigned short Vb[2][64 * 64];   // 2 x 8 KB, Vt[h][key] swizzled
  __shared__ __align__(16) unsigned short Pb[4][16 * 64];   // per-wave P, swizzled

  const int t    = threadIdx.x;
  const int wave = t >> 6;
  const int lane = t & 63;
  const int quad = lane >> 4;
  const int l16  = lane & 15;
  const int B0 = blockIdx.x;        // 64-row q-block
  const int c  = blockIdx.y;        // chunk
  const int b  = blockIdx.z;
  const int nch = (B0 >> 2) + 1;
  if (c >= nch) return;
  const int t0 = c * 4;
  const int t1 = min(t0 + 3, B0);
  const int qt = B0 * 4 + wave;
  const int q0 = qt * 16;

  const unsigned short* qg = qkv;
  const unsigned short* kg = qkv + QKVSZ;
  const unsigned short* vg = qkv + 2 * QKVSZ;     // vT[b][h][s]

  const unsigned short* qptr = qg + ((size_t)(b * SEQ + q0 + l16)) * HD + quad * 8;
  const bf16x8 qf0 = *(const bf16x8*)qptr;        // d 0..31
  const bf16x8 qf1 = *(const bf16x8*)(qptr + 32); // d 32..63

  f32x4 o0 = {0,0,0,0}, o1 = {0,0,0,0}, o2 = {0,0,0,0}, o3 = {0,0,0,0};
  float mst[4] = {-INFINITY, -INFINITY, -INFINITY, -INFINITY};
  float lst[4] = {0.f, 0.f, 0.f, 0.f};
  const float sc = 0.125f * 1.44269504088896f;    // 1/sqrt(64) * log2(e)

  // prologue: prefetch tile t0 (block-cooperative: 2 x 16B units per thread per matrix)
  bf16x8 kpre[2], vpre[2];
#pragma unroll
  for (int i = 0; i < 2; i++) {
    int u = t + i * 256;
    kpre[i] = *(const bf16x8*)(kg + ((size_t)(b * SEQ + t0 * 64 + (u >> 3))) * HD + (u & 7) * 8);
    vpre[i] = *(const bf16x8*)(vg + ((size_t)(b * 64 + (u >> 3))) * SEQ + t0 * 64 + (u & 7) * 8);
  }
#pragma unroll
  for (int i = 0; i < 2; i++) {
    int u = t + i * 256;
    int row = u >> 3, sb = (u & 7) * 16;
    *(bf16x8*)((char*)&Kb[0][0] + row * 128 + (sb ^ ((row & 7) << 4))) = kpre[i];
    *(bf16x8*)((char*)&Vb[0][0] + row * 128 + (sb ^ ((row & 7) << 4))) = vpre[i];
  }
  __syncthreads();

  for (int kb = t0; kb <= t1; kb++) {
    const int cur = (kb - t0) & 1;

    // issue next tile's global loads (latency hides under compute)
    if (kb < t1) {
#pragma unroll
      for (int i = 0; i < 2; i++) {
        int u = t + i * 256;
        kpre[i] = *(const bf16x8*)(kg + ((size_t)(b * SEQ + (kb + 1) * 64 + (u >> 3))) * HD + (u & 7) * 8);
        vpre[i] = *(const bf16x8*)(vg + ((size_t)(b * 64 + (u >> 3))) * SEQ + (kb + 1) * 64 + (u & 7) * 8);
      }
    }

    // S = Q K^T  (4 ktiles of 16 keys)
    f32x4 s[4];
#pragma unroll
    for (int kt = 0; kt < 4; kt++) {
      int row = kt * 16 + l16;
      bf16x8 kf0 = *(const bf16x8*)((char*)&Kb[cur][0] + row * 128 + ((quad * 16) ^ ((row & 7) << 4)));
      bf16x8 kf1 = *(const bf16x8*)((char*)&Kb[cur][0] + row * 128 + ((64 + quad * 16) ^ ((row & 7) << 4)));
      f32x4 z = {0.f, 0.f, 0.f, 0.f};
      z = __builtin_amdgcn_mfma_f32_16x16x32_bf16(qf0, kf0, z, 0, 0, 0);
      z = __builtin_amdgcn_mfma_f32_16x16x32_bf16(qf1, kf1, z, 0, 0, 0);
      s[kt] = z;
    }

    // scale; causal mask only on the diagonal tile (kb == B0)
    if (kb == B0) {
#pragma unroll
      for (int r = 0; r < 4; r++) {
        int rowg = q0 + quad * 4 + r;
#pragma unroll
        for (int kt = 0; kt < 4; kt++) {
          int col = kb * 64 + kt * 16 + l16;
          float v = s[kt][r] * sc;
          s[kt][r] = (col > rowg) ? -INFINITY : v;
        }
      }
    } else {
#pragma unroll
      for (int r = 0; r < 4; r++)
#pragma unroll
        for (int kt = 0; kt < 4; kt++) s[kt][r] *= sc;
    }

    // online softmax (reduce across the 16-lane col group)
    float alpha[4];
#pragma unroll
    for (int r = 0; r < 4; r++) {
      float mx = fmaxf(fmaxf(s[0][r], s[1][r]), fmaxf(s[2][r], s[3][r]));
#pragma unroll
      for (int off = 1; off < 16; off <<= 1) mx = fmaxf(mx, __shfl_xor(mx, off, 64));
      float mnew = fmaxf(mst[r], mx);
      alpha[r] = exp2f(mst[r] - mnew);
      mst[r] = mnew;
    }
#pragma unroll
    for (int r = 0; r < 4; r++) {
      float sm = 0.f;
#pragma unroll
      for (int kt = 0; kt < 4; kt++) {
        float p = exp2f(s[kt][r] - mst[r]);
        s[kt][r] = p;
        sm += p;
      }
#pragma unroll
      for (int off = 1; off < 16; off <<= 1) sm += __shfl_xor(sm, off, 64);
      lst[r] = lst[r] * alpha[r] + sm;
    }
#pragma unroll
    for (int r = 0; r < 4; r++) { o0[r] *= alpha[r]; o1[r] *= alpha[r]; o2[r] *= alpha[r]; o3[r] *= alpha[r]; }

    // P (C-layout) -> per-wave LDS bf16 (swizzled); wave-local dep, no barrier needed
#pragma unroll
    for (int kt = 0; kt < 4; kt++)
#pragma unroll
      for (int r = 0; r < 4; r++) {
        int row = quad * 4 + r;
        *(unsigned short*)((char*)&Pb[wave][0] + row * 128 +
                           ((kt * 32 + l16 * 2) ^ ((row & 7) << 4))) = f2b(s[kt][r]);
      }

    // O += P V
#pragma unroll
    for (int kc = 0; kc < 2; kc++) {
      bf16x8 pf = *(const bf16x8*)((char*)&Pb[wave][0] + l16 * 128 +
                                   ((kc * 64 + quad * 16) ^ ((l16 & 7) << 4)));
      int r0 = l16, r1 = 16 + l16, r2 = 32 + l16, r3 = 48 + l16;
      bf16x8 vf0 = *(const bf16x8*)((char*)&Vb[cur][0] + r0 * 128 + ((kc * 64 + quad * 16) ^ ((r0 & 7) << 4)));
      bf16x8 vf1 = *(const bf16x8*)((char*)&Vb[cur][0] + r1 * 128 + ((kc * 64 + quad * 16) ^ ((r1 & 7) << 4)));
      bf16x8 vf2 = *(const bf16x8*)((char*)&Vb[cur][0] + r2 * 128 + ((kc * 64 + quad * 16) ^ ((r2 & 7) << 4)));
      bf16x8 vf3 = *(const bf16x8*)((char*)&Vb[cur][0] + r3 * 128 + ((kc * 64 + quad * 16) ^ ((r3 & 7) << 4)));
      o0 = __builtin_amdgcn_mfma_f32_16x16x32_bf16(pf, vf0, o0, 0, 0, 0);
      o1 = __builtin_amdgcn_mfma_f32_16x16x32_bf16(pf, vf1, o1, 0, 0, 0);
      o2 = __builtin_amdgcn_mfma_f32_16x16x32_bf16(pf, vf2, o2, 0, 0, 0);
      o3 = __builtin_amdgcn_mfma_f32_16x16x32_bf16(pf, vf3, o3, 0, 0, 0);
    }

    // stage next tile into the other buffer; single barrier per step
    if (kb < t1) {
      const int nb = cur ^ 1;
#pragma unroll
      for (int i = 0; i < 2; i++) {
        int u = t + i * 256;
        int row = u >> 3, sb = (u & 7) * 16;
        *(bf16x8*)((char*)&Kb[nb][0] + row * 128 + (sb ^ ((row & 7) << 4))) = kpre[i];
        *(bf16x8*)((char*)&Vb[nb][0] + row * 128 + (sb ^ ((row & 7) << 4))) = vpre[i];
      }
    }
    __syncthreads();
  }

  if (nch == 1) {  // B0 < 4: single chunk, finalize directly
#pragma unroll
    for (int r = 0; r < 4; r++) {
      float inv = 1.f / lst[r];
      int rowg = q0 + quad * 4 + r;
      size_t ob = ((size_t)(b * SEQ + rowg)) * HD + l16;
      out[ob + 0]  = o0[r] * inv;
      out[ob + 16] = o1[r] * inv;
      out[ob + 32] = o2[r] * inv;
      out[ob + 48] = o3[r] * inv;
    }
  } else {         // write unnormalized partial + (m,l); row in [0,64) within qblock
    float* ps = part + ((size_t)((b * 32 + B0) * 8 + c)) * PSLOT2;
#pragma unroll
    for (int r = 0; r < 4; r++) {
      int row = wave * 16 + quad * 4 + r;
      ps[row * 64 + 0  + l16] = o0[r];
      ps[row * 64 + 16 + l16] = o1[r];
      ps[row * 64 + 32 + l16] = o2[r];
      ps[row * 64 + 48 + l16] = o3[r];
      if (l16 == 0) {
        ps[4096 + row] = mst[r];
        ps[4160 + row] = lst[r];
      }
    }
  }
}

// ---------------- merge nch partials per 64-row q-block ----------------
__global__ __launch_bounds__(256) void attn_merge(const float* __restrict__ part,
                                                  float* __restrict__ out) {
  const int B0 = blockIdx.x;
  const int b  = blockIdx.y;
  const int nch = (B0 >> 2) + 1;
  if (nch < 2) return;
  const int t  = threadIdx.x;
  const int h  = t & 63;
  const int rg = t >> 6;            // 4 row groups of 16
  const float* base = part + ((size_t)((b * 32 + B0) * 8)) * PSLOT2;
#pragma unroll 4
  for (int rr = 0; rr < 16; rr++) {
    int row = rg * 16 + rr;
    float M = -INFINITY;
    for (int cc = 0; cc < nch; cc++)
      M = fmaxf(M, base[(size_t)cc * PSLOT2 + 4096 + row]);
    float L = 0.f, o = 0.f;
    for (int cc = 0; cc < nch; cc++) {
      const float* ps = base + (size_t)cc * PSLOT2;
      float e = exp2f(ps[4096 + row] - M);
      L += ps[4160 + row] * e;
      o += ps[row * 64 + h] * e;
    }
    out[((size_t)(b * SEQ + B0 * 64 + row)) * HD + h] = o / L;
  }
}

extern "C" void kernel_launch(void* const* d_in, const int* in_sizes, int n_in,
                              void* d_out, int out_size, void* d_ws, size_t ws_size,
                              hipStream_t stream) {
  const float* emb = (const float*)d_in[0];
  const float* wq  = (const float*)d_in[1];
  const float* wk  = (const float*)d_in[2];
  const float* wv  = (const float*)d_in[3];
  unsigned short* ws  = (unsigned short*)d_ws;
  unsigned short* wt  = ws;              // 196608 bf16
  unsigned short* qkv = ws + WTSZ;       // q,k natural + vT  (3 x 1048576 bf16)
  float* part = (float*)(ws + WTSZ + 3 * QKVSZ);   // 8*32*8 slots x 4224 fp32 = 34.6 MB

  hipLaunchKernelGGL(wtrans_kernel,   dim3(WTSZ / 256), dim3(256), 0, stream, wq, wk, wv, wt);
  hipLaunchKernelGGL(qkv_proj_kernel, dim3(1024),       dim3(256), 0, stream, emb, wt, qkv);
  hipLaunchKernelGGL(attn_split,      dim3(32, 8, 8),   dim3(256), 0, stream, qkv, part, (float*)d_out);
  hipLaunchKernelGGL(attn_merge,      dim3(32, 8),      dim3(256), 0, stream, part, (float*)d_out);
}

// Round 5
// 160.048 us; speedup vs baseline: 1.3060x; 1.3060x over previous
//
#include <hip/hip_runtime.h>

#define SEQ   2048
#define NBATCH 8
#define EMB   1024
#define HD    64
#define QKVSZ (NBATCH * SEQ * HD)   /* 1048576 elems per matrix */
#define WTSZ  (3 * HD * EMB)        /* 196608 */
#define PSLOT2 4224                 /* 64*64 O + 64 m + 64 l */

typedef __attribute__((ext_vector_type(8))) short bf16x8;
typedef __attribute__((ext_vector_type(4))) float f32x4;

__device__ inline unsigned short f2b(float f) {
  union { float f; unsigned int i; } u; u.f = f;
  unsigned int r = (u.i + 0x7FFFu + ((u.i >> 16) & 1u)) >> 16;  // RNE
  return (unsigned short)r;
}

// ---------------- W transpose -> K-blocked layout [kb][m][c][kd] ----------------
__global__ __launch_bounds__(256) void wtrans_kernel(const float* __restrict__ wq,
                                                     const float* __restrict__ wk,
                                                     const float* __restrict__ wv,
                                                     unsigned short* __restrict__ wt) {
  int i = blockIdx.x * 256 + threadIdx.x;       // 0 .. 196607
  int kb  = i / 12288;
  int rem = i - kb * 12288;
  int m   = rem >> 12;          // 0..2
  int c   = (rem >> 6) & 63;    // output col within head
  int kd  = rem & 63;           // k within block
  const float* src = (m == 0) ? wq : ((m == 1) ? wk : wv);
  int d = kb * 64 + kd;
  wt[i] = f2b(src[d * 64 + c]);
}

// ---------------- QKV projection (R3 proven, verbatim) ----------------
__global__ __launch_bounds__(256, 4) void qkv_proj_kernel(const float* __restrict__ emb,
                                                          const unsigned short* __restrict__ wt,
                                                          unsigned short* __restrict__ qkv) {
  __shared__ __align__(16) unsigned short Ab[2][32 * 64];   // 8 KB  (row stride 128B, swizzled)
  __shared__ __align__(16) unsigned short Wb[2][96 * 64];   // 24 KB (col stride 128B, swizzled)

  const int t    = threadIdx.x;
  const int wave = t >> 6;
  const int lane = t & 63;
  const int quad = lane >> 4;
  const int l16  = lane & 15;
  const int bx = blockIdx.x;
  const int rt = bx >> 1;          // row tile (32 rows)
  const int ch = bx & 1;           // col half (96 cols)
  const int wr = wave >> 1;        // row sub-tile (16 rows)
  const int wc = wave & 1;         // col sub (48 cols = 3 MFMA tiles)

  const float* aBase = emb + (size_t)rt * 32 * EMB;
  const unsigned short* wBase = wt + ch * 6144;   // col-half offset within each kb chunk

  f32x4 acc[3];
#pragma unroll
  for (int j = 0; j < 3; j++) acc[j] = (f32x4){0.f, 0.f, 0.f, 0.f};

  f32x4 pa[2];
  bf16x8 pw[3];

  // ---- prologue: load tile kb=0 into regs, stage to buf0 ----
#pragma unroll
  for (int j = 0; j < 2; j++) {
    int u = t + j * 256;
    pa[j] = *(const f32x4*)(aBase + (size_t)(u >> 4) * EMB + (u & 15) * 4);
  }
#pragma unroll
  for (int j = 0; j < 3; j++) {
    int u = t + j * 256;
    pw[j] = *(const bf16x8*)(wBase + u * 8);
  }
#pragma unroll
  for (int j = 0; j < 2; j++) {
    int u = t + j * 256;
    int row = u >> 4, kq = u & 15;
    unsigned int lo = (unsigned int)f2b(pa[j][0]) | ((unsigned int)f2b(pa[j][1]) << 16);
    unsigned int hi = (unsigned int)f2b(pa[j][2]) | ((unsigned int)f2b(pa[j][3]) << 16);
    uint2 pk; pk.x = lo; pk.y = hi;
    *(uint2*)((char*)&Ab[0][0] + row * 128 + ((kq * 8) ^ ((row & 7) << 4))) = pk;
  }
#pragma unroll
  for (int j = 0; j < 3; j++) {
    int u = t + j * 256;
    int coll = u >> 3, kd8 = u & 7;
    *(bf16x8*)((char*)&Wb[0][0] + coll * 128 + ((kd8 ^ (coll & 7)) << 4)) = pw[j];
  }
  __syncthreads();

  // ---- main loop over 16 K-steps ----
#pragma unroll 2
  for (int kb = 0; kb < 16; kb++) {
    const int cur = kb & 1;

    if (kb < 15) {
#pragma unroll
      for (int j = 0; j < 2; j++) {
        int u = t + j * 256;
        pa[j] = *(const f32x4*)(aBase + (size_t)(u >> 4) * EMB + (kb + 1) * 64 + (u & 15) * 4);
      }
#pragma unroll
      for (int j = 0; j < 3; j++) {
        int u = t + j * 256;
        pw[j] = *(const bf16x8*)(wBase + (kb + 1) * 12288 + u * 8);
      }
    }

    const int arow = wr * 16 + l16;
#pragma unroll
    for (int kh = 0; kh < 2; kh++) {
      bf16x8 af = *(const bf16x8*)((const char*)&Ab[cur][0] + arow * 128 +
                                   ((kh * 64 + quad * 16) ^ ((arow & 7) << 4)));
#pragma unroll
      for (int j = 0; j < 3; j++) {
        const int coll = (wc * 3 + j) * 16 + l16;
        bf16x8 wf = *(const bf16x8*)((const char*)&Wb[cur][0] + coll * 128 +
                                     ((kh * 64 + quad * 16) ^ ((coll & 7) << 4)));
        acc[j] = __builtin_amdgcn_mfma_f32_16x16x32_bf16(af, wf, acc[j], 0, 0, 0);
      }
    }

    if (kb < 15) {
      const int nb = cur ^ 1;
#pragma unroll
      for (int j = 0; j < 2; j++) {
        int u = t + j * 256;
        int row = u >> 4, kq = u & 15;
        unsigned int lo = (unsigned int)f2b(pa[j][0]) | ((unsigned int)f2b(pa[j][1]) << 16);
        unsigned int hi = (unsigned int)f2b(pa[j][2]) | ((unsigned int)f2b(pa[j][3]) << 16);
        uint2 pk; pk.x = lo; pk.y = hi;
        *(uint2*)((char*)&Ab[nb][0] + row * 128 + ((kq * 8) ^ ((row & 7) << 4))) = pk;
      }
#pragma unroll
      for (int j = 0; j < 3; j++) {
        int u = t + j * 256;
        int coll = u >> 3, kd8 = u & 7;
        *(bf16x8*)((char*)&Wb[nb][0] + coll * 128 + ((kd8 ^ (coll & 7)) << 4)) = pw[j];
      }
      __syncthreads();
    }
  }

  // ---- epilogue: Q,K natural stores ----
#pragma unroll
  for (int j = 0; j < 3; j++) {
    int gc = ch * 96 + (wc * 3 + j) * 16 + l16;
    if (gc < 128) {                               // uniform per (wave,j)
      int m  = gc >> 6, cm = gc & 63;
#pragma unroll
      for (int r = 0; r < 4; r++) {
        int row = rt * 32 + wr * 16 + quad * 4 + r;   // C/D: row = quad*4+reg, col = l16
        qkv[(size_t)m * QKVSZ + (size_t)row * HD + cm] = f2b(acc[j][r]);
      }
    }
  }

  // ---- epilogue: V -> LDS transpose -> vT[b][h][s] coalesced store ----
  if (ch == 1) {
    __syncthreads();                               // LDS free after last MFMA
    unsigned short* Vsh = (unsigned short*)&Ab[0][0];   // 64 h x 40 pitch = 5120 shorts
#pragma unroll
    for (int j = 0; j < 3; j++) {
      int gc = 96 + (wc * 3 + j) * 16 + l16;
      if (gc >= 128) {
        int h = gc - 128;
#pragma unroll
        for (int r = 0; r < 4; r++)
          Vsh[h * 40 + wr * 16 + quad * 4 + r] = f2b(acc[j][r]);
      }
    }
    __syncthreads();
    int h  = t >> 2;
    int sq = (t & 3) * 8;
    int row0 = rt * 32;
    int b    = row0 >> 11;
    int seq0 = row0 & 2047;
    bf16x8 vv = *(const bf16x8*)(Vsh + h * 40 + sq);
    *(bf16x8*)(qkv + 2 * (size_t)QKVSZ + ((size_t)(b * 64 + h)) * SEQ + seq0 + sq) = vv;
  }
}

// ---------------- Flash attention: 4 waves/block, 64 q-rows, 4-tile split-K chunks --------
// (R4 proven, verbatim)
__global__ __launch_bounds__(256, 4) void attn_split(const unsigned short* __restrict__ qkv,
                                                     float* __restrict__ part,
                                                     float* __restrict__ out) {
  __shared__ __align__(16) unsigned short Kb[2][64 * 64];   // 2 x 8 KB, swizzled rows
  __shared__ __align__(16) unsigned short Vb[2][64 * 64];   // 2 x 8 KB, Vt[h][key] swizzled
  __shared__ __align__(16) unsigned short Pb[4][16 * 64];   // per-wave P, swizzled

  const int t    = threadIdx.x;
  const int wave = t >> 6;
  const int lane = t & 63;
  const int quad = lane >> 4;
  const int l16  = lane & 15;
  const int B0 = blockIdx.x;        // 64-row q-block
  const int c  = blockIdx.y;        // chunk
  const int b  = blockIdx.z;
  const int nch = (B0 >> 2) + 1;
  if (c >= nch) return;
  const int t0 = c * 4;
  const int t1 = min(t0 + 3, B0);
  const int qt = B0 * 4 + wave;
  const int q0 = qt * 16;

  const unsigned short* qg = qkv;
  const unsigned short* kg = qkv + QKVSZ;
  const unsigned short* vg = qkv + 2 * QKVSZ;     // vT[b][h][s]

  const unsigned short* qptr = qg + ((size_t)(b * SEQ + q0 + l16)) * HD + quad * 8;
  const bf16x8 qf0 = *(const bf16x8*)qptr;        // d 0..31
  const bf16x8 qf1 = *(const bf16x8*)(qptr + 32); // d 32..63

  f32x4 o0 = {0,0,0,0}, o1 = {0,0,0,0}, o2 = {0,0,0,0}, o3 = {0,0,0,0};
  float mst[4] = {-INFINITY, -INFINITY, -INFINITY, -INFINITY};
  float lst[4] = {0.f, 0.f, 0.f, 0.f};
  const float sc = 0.125f * 1.44269504088896f;    // 1/sqrt(64) * log2(e)

  // prologue: prefetch tile t0 (block-cooperative: 2 x 16B units per thread per matrix)
  bf16x8 kpre[2], vpre[2];
#pragma unroll
  for (int i = 0; i < 2; i++) {
    int u = t + i * 256;
    kpre[i] = *(const bf16x8*)(kg + ((size_t)(b * SEQ + t0 * 64 + (u >> 3))) * HD + (u & 7) * 8);
    vpre[i] = *(const bf16x8*)(vg + ((size_t)(b * 64 + (u >> 3))) * SEQ + t0 * 64 + (u & 7) * 8);
  }
#pragma unroll
  for (int i = 0; i < 2; i++) {
    int u = t + i * 256;
    int row = u >> 3, sb = (u & 7) * 16;
    *(bf16x8*)((char*)&Kb[0][0] + row * 128 + (sb ^ ((row & 7) << 4))) = kpre[i];
    *(bf16x8*)((char*)&Vb[0][0] + row * 128 + (sb ^ ((row & 7) << 4))) = vpre[i];
  }
  __syncthreads();

  for (int kb = t0; kb <= t1; kb++) {
    const int cur = (kb - t0) & 1;

    // issue next tile's global loads (latency hides under compute)
    if (kb < t1) {
#pragma unroll
      for (int i = 0; i < 2; i++) {
        int u = t + i * 256;
        kpre[i] = *(const bf16x8*)(kg + ((size_t)(b * SEQ + (kb + 1) * 64 + (u >> 3))) * HD + (u & 7) * 8);
        vpre[i] = *(const bf16x8*)(vg + ((size_t)(b * 64 + (u >> 3))) * SEQ + (kb + 1) * 64 + (u & 7) * 8);
      }
    }

    // S = Q K^T  (4 ktiles of 16 keys)
    f32x4 s[4];
#pragma unroll
    for (int kt = 0; kt < 4; kt++) {
      int row = kt * 16 + l16;
      bf16x8 kf0 = *(const bf16x8*)((char*)&Kb[cur][0] + row * 128 + ((quad * 16) ^ ((row & 7) << 4)));
      bf16x8 kf1 = *(const bf16x8*)((char*)&Kb[cur][0] + row * 128 + ((64 + quad * 16) ^ ((row & 7) << 4)));
      f32x4 z = {0.f, 0.f, 0.f, 0.f};
      z = __builtin_amdgcn_mfma_f32_16x16x32_bf16(qf0, kf0, z, 0, 0, 0);
      z = __builtin_amdgcn_mfma_f32_16x16x32_bf16(qf1, kf1, z, 0, 0, 0);
      s[kt] = z;
    }

    // scale; causal mask only on the diagonal tile (kb == B0)
    if (kb == B0) {
#pragma unroll
      for (int r = 0; r < 4; r++) {
        int rowg = q0 + quad * 4 + r;
#pragma unroll
        for (int kt = 0; kt < 4; kt++) {
          int col = kb * 64 + kt * 16 + l16;
          float v = s[kt][r] * sc;
          s[kt][r] = (col > rowg) ? -INFINITY : v;
        }
      }
    } else {
#pragma unroll
      for (int r = 0; r < 4; r++)
#pragma unroll
        for (int kt = 0; kt < 4; kt++) s[kt][r] *= sc;
    }

    // online softmax (reduce across the 16-lane col group)
    float alpha[4];
#pragma unroll
    for (int r = 0; r < 4; r++) {
      float mx = fmaxf(fmaxf(s[0][r], s[1][r]), fmaxf(s[2][r], s[3][r]));
#pragma unroll
      for (int off = 1; off < 16; off <<= 1) mx = fmaxf(mx, __shfl_xor(mx, off, 64));
      float mnew = fmaxf(mst[r], mx);
      alpha[r] = exp2f(mst[r] - mnew);
      mst[r] = mnew;
    }
#pragma unroll
    for (int r = 0; r < 4; r++) {
      float sm = 0.f;
#pragma unroll
      for (int kt = 0; kt < 4; kt++) {
        float p = exp2f(s[kt][r] - mst[r]);
        s[kt][r] = p;
        sm += p;
      }
#pragma unroll
      for (int off = 1; off < 16; off <<= 1) sm += __shfl_xor(sm, off, 64);
      lst[r] = lst[r] * alpha[r] + sm;
    }
#pragma unroll
    for (int r = 0; r < 4; r++) { o0[r] *= alpha[r]; o1[r] *= alpha[r]; o2[r] *= alpha[r]; o3[r] *= alpha[r]; }

    // P (C-layout) -> per-wave LDS bf16 (swizzled); wave-local dep, no barrier needed
#pragma unroll
    for (int kt = 0; kt < 4; kt++)
#pragma unroll
      for (int r = 0; r < 4; r++) {
        int row = quad * 4 + r;
        *(unsigned short*)((char*)&Pb[wave][0] + row * 128 +
                           ((kt * 32 + l16 * 2) ^ ((row & 7) << 4))) = f2b(s[kt][r]);
      }

    // O += P V
#pragma unroll
    for (int kc = 0; kc < 2; kc++) {
      bf16x8 pf = *(const bf16x8*)((char*)&Pb[wave][0] + l16 * 128 +
                                   ((kc * 64 + quad * 16) ^ ((l16 & 7) << 4)));
      int r0 = l16, r1 = 16 + l16, r2 = 32 + l16, r3 = 48 + l16;
      bf16x8 vf0 = *(const bf16x8*)((char*)&Vb[cur][0] + r0 * 128 + ((kc * 64 + quad * 16) ^ ((r0 & 7) << 4)));
      bf16x8 vf1 = *(const bf16x8*)((char*)&Vb[cur][0] + r1 * 128 + ((kc * 64 + quad * 16) ^ ((r1 & 7) << 4)));
      bf16x8 vf2 = *(const bf16x8*)((char*)&Vb[cur][0] + r2 * 128 + ((kc * 64 + quad * 16) ^ ((r2 & 7) << 4)));
      bf16x8 vf3 = *(const bf16x8*)((char*)&Vb[cur][0] + r3 * 128 + ((kc * 64 + quad * 16) ^ ((r3 & 7) << 4)));
      o0 = __builtin_amdgcn_mfma_f32_16x16x32_bf16(pf, vf0, o0, 0, 0, 0);
      o1 = __builtin_amdgcn_mfma_f32_16x16x32_bf16(pf, vf1, o1, 0, 0, 0);
      o2 = __builtin_amdgcn_mfma_f32_16x16x32_bf16(pf, vf2, o2, 0, 0, 0);
      o3 = __builtin_amdgcn_mfma_f32_16x16x32_bf16(pf, vf3, o3, 0, 0, 0);
    }

    // stage next tile into the other buffer; single barrier per step
    if (kb < t1) {
      const int nb = cur ^ 1;
#pragma unroll
      for (int i = 0; i < 2; i++) {
        int u = t + i * 256;
        int row = u >> 3, sb = (u & 7) * 16;
        *(bf16x8*)((char*)&Kb[nb][0] + row * 128 + (sb ^ ((row & 7) << 4))) = kpre[i];
        *(bf16x8*)((char*)&Vb[nb][0] + row * 128 + (sb ^ ((row & 7) << 4))) = vpre[i];
      }
    }
    __syncthreads();
  }

  if (nch == 1) {  // B0 < 4: single chunk, finalize directly
#pragma unroll
    for (int r = 0; r < 4; r++) {
      float inv = 1.f / lst[r];
      int rowg = q0 + quad * 4 + r;
      size_t ob = ((size_t)(b * SEQ + rowg)) * HD + l16;
      out[ob + 0]  = o0[r] * inv;
      out[ob + 16] = o1[r] * inv;
      out[ob + 32] = o2[r] * inv;
      out[ob + 48] = o3[r] * inv;
    }
  } else {         // write unnormalized partial + (m,l); row in [0,64) within qblock
    float* ps = part + ((size_t)((b * 32 + B0) * 8 + c)) * PSLOT2;
#pragma unroll
    for (int r = 0; r < 4; r++) {
      int row = wave * 16 + quad * 4 + r;
      ps[row * 64 + 0  + l16] = o0[r];
      ps[row * 64 + 16 + l16] = o1[r];
      ps[row * 64 + 32 + l16] = o2[r];
      ps[row * 64 + 48 + l16] = o3[r];
      if (l16 == 0) {
        ps[4096 + row] = mst[r];
        ps[4160 + row] = lst[r];
      }
    }
  }
}

// ---------------- merge nch partials per 64-row q-block ----------------
// grid (112, 8): bx = (B0-4)*4 + rg, B0 in [4,32), rg = row-group of 16.
// Fully unrolled 8-chunk accumulation with clamped addresses -> all loads in flight at once.
__global__ __launch_bounds__(256) void attn_merge(const float* __restrict__ part,
                                                  float* __restrict__ out) {
  const int bx = blockIdx.x;
  const int B0 = 4 + (bx >> 2);
  const int rg = bx & 3;
  const int b  = blockIdx.y;
  const int nch = (B0 >> 2) + 1;    // 2..8
  const int t  = threadIdx.x;
  const int h  = t & 63;
  const int rloc = t >> 6;          // 0..3
  const float* base = part + ((size_t)((b * 32 + B0) * 8)) * PSLOT2;
#pragma unroll
  for (int i = 0; i < 4; i++) {
    int row = rg * 16 + rloc * 4 + i;
    float mv[8], lv[8], ov[8];
#pragma unroll
    for (int cc = 0; cc < 8; cc++) {
      int cs = (cc < nch) ? cc : 0;                 // clamp: valid address, masked later
      const float* ps = base + (size_t)cs * PSLOT2;
      mv[cc] = ps[4096 + row];
      lv[cc] = ps[4160 + row];
      ov[cc] = ps[row * 64 + h];
    }
    float M = -INFINITY;
#pragma unroll
    for (int cc = 0; cc < 8; cc++) M = fmaxf(M, (cc < nch) ? mv[cc] : -INFINITY);
    float L = 0.f, o = 0.f;
#pragma unroll
    for (int cc = 0; cc < 8; cc++) {
      float e = (cc < nch) ? exp2f(mv[cc] - M) : 0.f;
      L += lv[cc] * e;
      o += ov[cc] * e;
    }
    out[((size_t)(b * SEQ + B0 * 64 + row)) * HD + h] = o / L;
  }
}

extern "C" void kernel_launch(void* const* d_in, const int* in_sizes, int n_in,
                              void* d_out, int out_size, void* d_ws, size_t ws_size,
                              hipStream_t stream) {
  const float* emb = (const float*)d_in[0];
  const float* wq  = (const float*)d_in[1];
  const float* wk  = (const float*)d_in[2];
  const float* wv  = (const float*)d_in[3];
  unsigned short* ws  = (unsigned short*)d_ws;
  unsigned short* wt  = ws;              // 196608 bf16
  unsigned short* qkv = ws + WTSZ;       // q,k natural + vT  (3 x 1048576 bf16)
  float* part = (float*)(ws + WTSZ + 3 * QKVSZ);   // 8*32*8 slots x 4224 fp32 = 34.6 MB

  hipLaunchKernelGGL(wtrans_kernel,   dim3(WTSZ / 256), dim3(256), 0, stream, wq, wk, wv, wt);
  hipLaunchKernelGGL(qkv_proj_kernel, dim3(1024),       dim3(256), 0, stream, emb, wt, qkv);
  hipLaunchKernelGGL(attn_split,      dim3(32, 8, 8),   dim3(256), 0, stream, qkv, part, (float*)d_out);
  hipLaunchKernelGGL(attn_merge,      dim3(112, 8),     dim3(256), 0, stream, part, (float*)d_out);
}

// Round 6
// 159.188 us; speedup vs baseline: 1.3130x; 1.0054x over previous
//
#include <hip/hip_runtime.h>

#define SEQ   2048
#define NBATCH 8
#define EMB   1024
#define HD    64
#define QKVSZ (NBATCH * SEQ * HD)   /* 1048576 elems per matrix */
#define WTSZ  (3 * HD * EMB)        /* 196608 */
#define PSLOT2 4224                 /* 64*64 O + 64 m + 64 l */

typedef __attribute__((ext_vector_type(8))) short bf16x8;
typedef __attribute__((ext_vector_type(4))) float f32x4;

__device__ inline unsigned short f2b(float f) {
  union { float f; unsigned int i; } u; u.f = f;
  unsigned int r = (u.i + 0x7FFFu + ((u.i >> 16) & 1u)) >> 16;  // RNE
  return (unsigned short)r;
}

// ---------------- W transpose -> K-blocked layout [kb][m][c][kd] ----------------
__global__ __launch_bounds__(256) void wtrans_kernel(const float* __restrict__ wq,
                                                     const float* __restrict__ wk,
                                                     const float* __restrict__ wv,
                                                     unsigned short* __restrict__ wt) {
  int i = blockIdx.x * 256 + threadIdx.x;       // 0 .. 196607
  int kb  = i / 12288;
  int rem = i - kb * 12288;
  int m   = rem >> 12;          // 0..2
  int c   = (rem >> 6) & 63;    // output col within head
  int kd  = rem & 63;           // k within block
  const float* src = (m == 0) ? wq : ((m == 1) ? wk : wv);
  int d = kb * 64 + kd;
  wt[i] = f2b(src[d * 64 + c]);
}

// ---------------- QKV projection: depth-2 pipelined LDS-staged GEMM ----------------
// [16384 x 1024] fp32  x  [1024 x 192] bf16.  BM=32, BN=96 (col-half), BK=64.
// Loads for tile k+2 issued during step k; staged during step k+1; consumed step k+2.
// Loads are ~1.5 steps old when the ds_write's s_waitcnt hits -> no exposed HBM latency.
// Two named register sets (no runtime indexing), unroll-by-2; one barrier per step.
#define QKV_ISSUE(kb, pa, pw)                                                       \
  do {                                                                              \
    _Pragma("unroll") for (int j = 0; j < 2; j++) {                                 \
      int u = t + j * 256;                                                          \
      pa[j] = *(const f32x4*)(aBase + (size_t)(u >> 4) * EMB + (kb) * 64 + (u & 15) * 4); \
    }                                                                               \
    _Pragma("unroll") for (int j = 0; j < 3; j++) {                                 \
      int u = t + j * 256;                                                          \
      pw[j] = *(const bf16x8*)(wBase + (size_t)(kb) * 12288 + u * 8);               \
    }                                                                               \
  } while (0)

#define QKV_STAGE(buf, pa, pw)                                                      \
  do {                                                                              \
    _Pragma("unroll") for (int j = 0; j < 2; j++) {                                 \
      int u = t + j * 256;                                                          \
      int row = u >> 4, kq = u & 15;                                                \
      unsigned int lo = (unsigned int)f2b(pa[j][0]) | ((unsigned int)f2b(pa[j][1]) << 16); \
      unsigned int hi = (unsigned int)f2b(pa[j][2]) | ((unsigned int)f2b(pa[j][3]) << 16); \
      uint2 pk; pk.x = lo; pk.y = hi;                                               \
      *(uint2*)((char*)&Ab[buf][0] + row * 128 + ((kq * 8) ^ ((row & 7) << 4))) = pk; \
    }                                                                               \
    _Pragma("unroll") for (int j = 0; j < 3; j++) {                                 \
      int u = t + j * 256;                                                          \
      int coll = u >> 3, kd8 = u & 7;                                               \
      *(bf16x8*)((char*)&Wb[buf][0] + coll * 128 + ((kd8 ^ (coll & 7)) << 4)) = pw[j]; \
    }                                                                               \
  } while (0)

#define QKV_COMPUTE(buf)                                                            \
  do {                                                                              \
    const int arow = wr * 16 + l16;                                                 \
    _Pragma("unroll") for (int kh = 0; kh < 2; kh++) {                              \
      bf16x8 af = *(const bf16x8*)((const char*)&Ab[buf][0] + arow * 128 +          \
                                   ((kh * 64 + quad * 16) ^ ((arow & 7) << 4)));    \
      _Pragma("unroll") for (int j = 0; j < 3; j++) {                               \
        const int coll = (wc * 3 + j) * 16 + l16;                                   \
        bf16x8 wf = *(const bf16x8*)((const char*)&Wb[buf][0] + coll * 128 +        \
                                     ((kh * 64 + quad * 16) ^ ((coll & 7) << 4)));  \
        acc[j] = __builtin_amdgcn_mfma_f32_16x16x32_bf16(af, wf, acc[j], 0, 0, 0);  \
      }                                                                             \
    }                                                                               \
  } while (0)

__global__ __launch_bounds__(256, 4) void qkv_proj_kernel(const float* __restrict__ emb,
                                                          const unsigned short* __restrict__ wt,
                                                          unsigned short* __restrict__ qkv) {
  __shared__ __align__(16) unsigned short Ab[2][32 * 64];   // 8 KB  (row stride 128B, swizzled)
  __shared__ __align__(16) unsigned short Wb[2][96 * 64];   // 24 KB (col stride 128B, swizzled)

  const int t    = threadIdx.x;
  const int wave = t >> 6;
  const int lane = t & 63;
  const int quad = lane >> 4;
  const int l16  = lane & 15;
  const int bx = blockIdx.x;
  const int rt = bx >> 1;          // row tile (32 rows)
  const int ch = bx & 1;           // col half (96 cols)
  const int wr = wave >> 1;        // row sub-tile (16 rows)
  const int wc = wave & 1;         // col sub (48 cols = 3 MFMA tiles)

  const float* aBase = emb + (size_t)rt * 32 * EMB;
  const unsigned short* wBase = wt + ch * 6144;   // col-half offset within each kb chunk

  f32x4 acc[3];
#pragma unroll
  for (int j = 0; j < 3; j++) acc[j] = (f32x4){0.f, 0.f, 0.f, 0.f};

  f32x4 paA[2], paB[2];
  bf16x8 pwA[3], pwB[3];

  // ---- prologue: issue L0, L1; stage L0 (waits only L0: compiler leaves L1 in flight) ----
  QKV_ISSUE(0, paA, pwA);
  QKV_ISSUE(1, paB, pwB);
  QKV_STAGE(0, paA, pwA);
  __syncthreads();

  // ---- main loop, unroll-by-2: named register sets alternate ----
#pragma unroll
  for (int k = 0; k < 16; k += 2) {
    // even step k: compute buf0 (=Lk); stage L(k+1) from setB -> buf1; issue L(k+2) -> setA
    if (k + 2 < 16) QKV_ISSUE(k + 2, paA, pwA);
    QKV_COMPUTE(0);
    if (k + 1 < 16) QKV_STAGE(1, paB, pwB);
    __syncthreads();
    // odd step k+1: compute buf1; stage L(k+2) from setA -> buf0; issue L(k+3) -> setB
    if (k + 3 < 16) QKV_ISSUE(k + 3, paB, pwB);
    QKV_COMPUTE(1);
    if (k + 2 < 16) QKV_STAGE(0, paA, pwA);
    __syncthreads();
  }

  // ---- epilogue: Q,K natural stores ----
#pragma unroll
  for (int j = 0; j < 3; j++) {
    int gc = ch * 96 + (wc * 3 + j) * 16 + l16;
    if (gc < 128) {                               // uniform per (wave,j)
      int m  = gc >> 6, cm = gc & 63;
#pragma unroll
      for (int r = 0; r < 4; r++) {
        int row = rt * 32 + wr * 16 + quad * 4 + r;   // C/D: row = quad*4+reg, col = l16
        qkv[(size_t)m * QKVSZ + (size_t)row * HD + cm] = f2b(acc[j][r]);
      }
    }
  }

  // ---- epilogue: V -> LDS transpose -> vT[b][h][s] coalesced store ----
  if (ch == 1) {
    __syncthreads();                               // LDS free after last MFMA
    unsigned short* Vsh = (unsigned short*)&Ab[0][0];   // 64 h x 40 pitch = 5120 shorts
#pragma unroll
    for (int j = 0; j < 3; j++) {
      int gc = 96 + (wc * 3 + j) * 16 + l16;
      if (gc >= 128) {
        int h = gc - 128;
#pragma unroll
        for (int r = 0; r < 4; r++)
          Vsh[h * 40 + wr * 16 + quad * 4 + r] = f2b(acc[j][r]);
      }
    }
    __syncthreads();
    int h  = t >> 2;
    int sq = (t & 3) * 8;
    int row0 = rt * 32;
    int b    = row0 >> 11;
    int seq0 = row0 & 2047;
    bf16x8 vv = *(const bf16x8*)(Vsh + h * 40 + sq);
    *(bf16x8*)(qkv + 2 * (size_t)QKVSZ + ((size_t)(b * 64 + h)) * SEQ + seq0 + sq) = vv;
  }
}

// ---------------- Flash attention: 4 waves/block, 64 q-rows, 4-tile split-K chunks --------
// (R4 proven, verbatim)
__global__ __launch_bounds__(256, 4) void attn_split(const unsigned short* __restrict__ qkv,
                                                     float* __restrict__ part,
                                                     float* __restrict__ out) {
  __shared__ __align__(16) unsigned short Kb[2][64 * 64];   // 2 x 8 KB, swizzled rows
  __shared__ __align__(16) unsigned short Vb[2][64 * 64];   // 2 x 8 KB, Vt[h][key] swizzled
  __shared__ __align__(16) unsigned short Pb[4][16 * 64];   // per-wave P, swizzled

  const int t    = threadIdx.x;
  const int wave = t >> 6;
  const int lane = t & 63;
  const int quad = lane >> 4;
  const int l16  = lane & 15;
  const int B0 = blockIdx.x;        // 64-row q-block
  const int c  = blockIdx.y;        // chunk
  const int b  = blockIdx.z;
  const int nch = (B0 >> 2) + 1;
  if (c >= nch) return;
  const int t0 = c * 4;
  const int t1 = min(t0 + 3, B0);
  const int qt = B0 * 4 + wave;
  const int q0 = qt * 16;

  const unsigned short* qg = qkv;
  const unsigned short* kg = qkv + QKVSZ;
  const unsigned short* vg = qkv + 2 * QKVSZ;     // vT[b][h][s]

  const unsigned short* qptr = qg + ((size_t)(b * SEQ + q0 + l16)) * HD + quad * 8;
  const bf16x8 qf0 = *(const bf16x8*)qptr;        // d 0..31
  const bf16x8 qf1 = *(const bf16x8*)(qptr + 32); // d 32..63

  f32x4 o0 = {0,0,0,0}, o1 = {0,0,0,0}, o2 = {0,0,0,0}, o3 = {0,0,0,0};
  float mst[4] = {-INFINITY, -INFINITY, -INFINITY, -INFINITY};
  float lst[4] = {0.f, 0.f, 0.f, 0.f};
  const float sc = 0.125f * 1.44269504088896f;    // 1/sqrt(64) * log2(e)

  // prologue: prefetch tile t0 (block-cooperative: 2 x 16B units per thread per matrix)
  bf16x8 kpre[2], vpre[2];
#pragma unroll
  for (int i = 0; i < 2; i++) {
    int u = t + i * 256;
    kpre[i] = *(const bf16x8*)(kg + ((size_t)(b * SEQ + t0 * 64 + (u >> 3))) * HD + (u & 7) * 8);
    vpre[i] = *(const bf16x8*)(vg + ((size_t)(b * 64 + (u >> 3))) * SEQ + t0 * 64 + (u & 7) * 8);
  }
#pragma unroll
  for (int i = 0; i < 2; i++) {
    int u = t + i * 256;
    int row = u >> 3, sb = (u & 7) * 16;
    *(bf16x8*)((char*)&Kb[0][0] + row * 128 + (sb ^ ((row & 7) << 4))) = kpre[i];
    *(bf16x8*)((char*)&Vb[0][0] + row * 128 + (sb ^ ((row & 7) << 4))) = vpre[i];
  }
  __syncthreads();

  for (int kb = t0; kb <= t1; kb++) {
    const int cur = (kb - t0) & 1;

    // issue next tile's global loads (latency hides under compute)
    if (kb < t1) {
#pragma unroll
      for (int i = 0; i < 2; i++) {
        int u = t + i * 256;
        kpre[i] = *(const bf16x8*)(kg + ((size_t)(b * SEQ + (kb + 1) * 64 + (u >> 3))) * HD + (u & 7) * 8);
        vpre[i] = *(const bf16x8*)(vg + ((size_t)(b * 64 + (u >> 3))) * SEQ + (kb + 1) * 64 + (u & 7) * 8);
      }
    }

    // S = Q K^T  (4 ktiles of 16 keys)
    f32x4 s[4];
#pragma unroll
    for (int kt = 0; kt < 4; kt++) {
      int row = kt * 16 + l16;
      bf16x8 kf0 = *(const bf16x8*)((char*)&Kb[cur][0] + row * 128 + ((quad * 16) ^ ((row & 7) << 4)));
      bf16x8 kf1 = *(const bf16x8*)((char*)&Kb[cur][0] + row * 128 + ((64 + quad * 16) ^ ((row & 7) << 4)));
      f32x4 z = {0.f, 0.f, 0.f, 0.f};
      z = __builtin_amdgcn_mfma_f32_16x16x32_bf16(qf0, kf0, z, 0, 0, 0);
      z = __builtin_amdgcn_mfma_f32_16x16x32_bf16(qf1, kf1, z, 0, 0, 0);
      s[kt] = z;
    }

    // scale; causal mask only on the diagonal tile (kb == B0)
    if (kb == B0) {
#pragma unroll
      for (int r = 0; r < 4; r++) {
        int rowg = q0 + quad * 4 + r;
#pragma unroll
        for (int kt = 0; kt < 4; kt++) {
          int col = kb * 64 + kt * 16 + l16;
          float v = s[kt][r] * sc;
          s[kt][r] = (col > rowg) ? -INFINITY : v;
        }
      }
    } else {
#pragma unroll
      for (int r = 0; r < 4; r++)
#pragma unroll
        for (int kt = 0; kt < 4; kt++) s[kt][r] *= sc;
    }

    // online softmax (reduce across the 16-lane col group)
    float alpha[4];
#pragma unroll
    for (int r = 0; r < 4; r++) {
      float mx = fmaxf(fmaxf(s[0][r], s[1][r]), fmaxf(s[2][r], s[3][r]));
#pragma unroll
      for (int off = 1; off < 16; off <<= 1) mx = fmaxf(mx, __shfl_xor(mx, off, 64));
      float mnew = fmaxf(mst[r], mx);
      alpha[r] = exp2f(mst[r] - mnew);
      mst[r] = mnew;
    }
#pragma unroll
    for (int r = 0; r < 4; r++) {
      float sm = 0.f;
#pragma unroll
      for (int kt = 0; kt < 4; kt++) {
        float p = exp2f(s[kt][r] - mst[r]);
        s[kt][r] = p;
        sm += p;
      }
#pragma unroll
      for (int off = 1; off < 16; off <<= 1) sm += __shfl_xor(sm, off, 64);
      lst[r] = lst[r] * alpha[r] + sm;
    }
#pragma unroll
    for (int r = 0; r < 4; r++) { o0[r] *= alpha[r]; o1[r] *= alpha[r]; o2[r] *= alpha[r]; o3[r] *= alpha[r]; }

    // P (C-layout) -> per-wave LDS bf16 (swizzled); wave-local dep, no barrier needed
#pragma unroll
    for (int kt = 0; kt < 4; kt++)
#pragma unroll
      for (int r = 0; r < 4; r++) {
        int row = quad * 4 + r;
        *(unsigned short*)((char*)&Pb[wave][0] + row * 128 +
                           ((kt * 32 + l16 * 2) ^ ((row & 7) << 4))) = f2b(s[kt][r]);
      }

    // O += P V
#pragma unroll
    for (int kc = 0; kc < 2; kc++) {
      bf16x8 pf = *(const bf16x8*)((char*)&Pb[wave][0] + l16 * 128 +
                                   ((kc * 64 + quad * 16) ^ ((l16 & 7) << 4)));
      int r0 = l16, r1 = 16 + l16, r2 = 32 + l16, r3 = 48 + l16;
      bf16x8 vf0 = *(const bf16x8*)((char*)&Vb[cur][0] + r0 * 128 + ((kc * 64 + quad * 16) ^ ((r0 & 7) << 4)));
      bf16x8 vf1 = *(const bf16x8*)((char*)&Vb[cur][0] + r1 * 128 + ((kc * 64 + quad * 16) ^ ((r1 & 7) << 4)));
      bf16x8 vf2 = *(const bf16x8*)((char*)&Vb[cur][0] + r2 * 128 + ((kc * 64 + quad * 16) ^ ((r2 & 7) << 4)));
      bf16x8 vf3 = *(const bf16x8*)((char*)&Vb[cur][0] + r3 * 128 + ((kc * 64 + quad * 16) ^ ((r3 & 7) << 4)));
      o0 = __builtin_amdgcn_mfma_f32_16x16x32_bf16(pf, vf0, o0, 0, 0, 0);
      o1 = __builtin_amdgcn_mfma_f32_16x16x32_bf16(pf, vf1, o1, 0, 0, 0);
      o2 = __builtin_amdgcn_mfma_f32_16x16x32_bf16(pf, vf2, o2, 0, 0, 0);
      o3 = __builtin_amdgcn_mfma_f32_16x16x32_bf16(pf, vf3, o3, 0, 0, 0);
    }

    // stage next tile into the other buffer; single barrier per step
    if (kb < t1) {
      const int nb = cur ^ 1;
#pragma unroll
      for (int i = 0; i < 2; i++) {
        int u = t + i * 256;
        int row = u >> 3, sb = (u & 7) * 16;
        *(bf16x8*)((char*)&Kb[nb][0] + row * 128 + (sb ^ ((row & 7) << 4))) = kpre[i];
        *(bf16x8*)((char*)&Vb[nb][0] + row * 128 + (sb ^ ((row & 7) << 4))) = vpre[i];
      }
    }
    __syncthreads();
  }

  if (nch == 1) {  // B0 < 4: single chunk, finalize directly
#pragma unroll
    for (int r = 0; r < 4; r++) {
      float inv = 1.f / lst[r];
      int rowg = q0 + quad * 4 + r;
      size_t ob = ((size_t)(b * SEQ + rowg)) * HD + l16;
      out[ob + 0]  = o0[r] * inv;
      out[ob + 16] = o1[r] * inv;
      out[ob + 32] = o2[r] * inv;
      out[ob + 48] = o3[r] * inv;
    }
  } else {         // write unnormalized partial + (m,l); row in [0,64) within qblock
    float* ps = part + ((size_t)((b * 32 + B0) * 8 + c)) * PSLOT2;
#pragma unroll
    for (int r = 0; r < 4; r++) {
      int row = wave * 16 + quad * 4 + r;
      ps[row * 64 + 0  + l16] = o0[r];
      ps[row * 64 + 16 + l16] = o1[r];
      ps[row * 64 + 32 + l16] = o2[r];
      ps[row * 64 + 48 + l16] = o3[r];
      if (l16 == 0) {
        ps[4096 + row] = mst[r];
        ps[4160 + row] = lst[r];
      }
    }
  }
}

// ---------------- merge nch partials per 64-row q-block ----------------
// grid (112, 8): bx = (B0-4)*4 + rg, B0 in [4,32), rg = row-group of 16.
// Fully unrolled 8-chunk accumulation with clamped addresses -> all loads in flight at once.
__global__ __launch_bounds__(256) void attn_merge(const float* __restrict__ part,
                                                  float* __restrict__ out) {
  const int bx = blockIdx.x;
  const int B0 = 4 + (bx >> 2);
  const int rg = bx & 3;
  const int b  = blockIdx.y;
  const int nch = (B0 >> 2) + 1;    // 2..8
  const int t  = threadIdx.x;
  const int h  = t & 63;
  const int rloc = t >> 6;          // 0..3
  const float* base = part + ((size_t)((b * 32 + B0) * 8)) * PSLOT2;
#pragma unroll
  for (int i = 0; i < 4; i++) {
    int row = rg * 16 + rloc * 4 + i;
    float mv[8], lv[8], ov[8];
#pragma unroll
    for (int cc = 0; cc < 8; cc++) {
      int cs = (cc < nch) ? cc : 0;                 // clamp: valid address, masked later
      const float* ps = base + (size_t)cs * PSLOT2;
      mv[cc] = ps[4096 + row];
      lv[cc] = ps[4160 + row];
      ov[cc] = ps[row * 64 + h];
    }
    float M = -INFINITY;
#pragma unroll
    for (int cc = 0; cc < 8; cc++) M = fmaxf(M, (cc < nch) ? mv[cc] : -INFINITY);
    float L = 0.f, o = 0.f;
#pragma unroll
    for (int cc = 0; cc < 8; cc++) {
      float e = (cc < nch) ? exp2f(mv[cc] - M) : 0.f;
      L += lv[cc] * e;
      o += ov[cc] * e;
    }
    out[((size_t)(b * SEQ + B0 * 64 + row)) * HD + h] = o / L;
  }
}

extern "C" void kernel_launch(void* const* d_in, const int* in_sizes, int n_in,
                              void* d_out, int out_size, void* d_ws, size_t ws_size,
                              hipStream_t stream) {
  const float* emb = (const float*)d_in[0];
  const float* wq  = (const float*)d_in[1];
  const float* wk  = (const float*)d_in[2];
  const float* wv  = (const float*)d_in[3];
  unsigned short* ws  = (unsigned short*)d_ws;
  unsigned short* wt  = ws;              // 196608 bf16
  unsigned short* qkv = ws + WTSZ;       // q,k natural + vT  (3 x 1048576 bf16)
  float* part = (float*)(ws + WTSZ + 3 * QKVSZ);   // 8*32*8 slots x 4224 fp32 = 34.6 MB

  hipLaunchKernelGGL(wtrans_kernel,   dim3(WTSZ / 256), dim3(256), 0, stream, wq, wk, wv, wt);
  hipLaunchKernelGGL(qkv_proj_kernel, dim3(1024),       dim3(256), 0, stream, emb, wt, qkv);
  hipLaunchKernelGGL(attn_split,      dim3(32, 8, 8),   dim3(256), 0, stream, qkv, part, (float*)d_out);
  hipLaunchKernelGGL(attn_merge,      dim3(112, 8),     dim3(256), 0, stream, part, (float*)d_out);
}

// Round 7
// 155.862 us; speedup vs baseline: 1.3410x; 1.0213x over previous
//
#include <hip/hip_runtime.h>

#define SEQ   2048
#define NBATCH 8
#define EMB   1024
#define HD    64
#define QKVSZ (NBATCH * SEQ * HD)   /* 1048576 elems per matrix */
#define WTSZ  (3 * HD * EMB)        /* 196608 */
#define PSLOT2 4224                 /* 64*64 O + 64 m + 64 l */

typedef __attribute__((ext_vector_type(8))) short bf16x8;
typedef __attribute__((ext_vector_type(4))) float f32x4;

__device__ inline unsigned short f2b(float f) {
  union { float f; unsigned int i; } u; u.f = f;
  unsigned int r = (u.i + 0x7FFFu + ((u.i >> 16) & 1u)) >> 16;  // RNE
  return (unsigned short)r;
}

// Direct global->LDS DMA, 16B per lane. LDS dest = uniform base + lane*16 (linear);
// swizzle is applied on the per-lane GLOBAL source address (inverse), read-side keeps XOR.
#define GLOAD_LDS16(g, l)                                              \
  __builtin_amdgcn_global_load_lds(                                    \
      (const __attribute__((address_space(1))) void*)(g),              \
      (__attribute__((address_space(3))) void*)(l), 16, 0, 0)

// ---------------- W transpose -> K-blocked layout [kb][m][c][kd] ----------------
__global__ __launch_bounds__(256) void wtrans_kernel(const float* __restrict__ wq,
                                                     const float* __restrict__ wk,
                                                     const float* __restrict__ wv,
                                                     unsigned short* __restrict__ wt) {
  int i = blockIdx.x * 256 + threadIdx.x;       // 0 .. 196607
  int kb  = i / 12288;
  int rem = i - kb * 12288;
  int m   = rem >> 12;          // 0..2
  int c   = (rem >> 6) & 63;    // output col within head
  int kd  = rem & 63;           // k within block
  const float* src = (m == 0) ? wq : ((m == 1) ? wk : wv);
  int d = kb * 64 + kd;
  wt[i] = f2b(src[d * 64 + c]);
}

// ---------------- QKV projection: W via global_load_lds, A reg-staged ----------------
// [16384 x 1024] fp32  x  [1024 x 192] bf16.  BM=32, BN=96 (col-half), BK=64.
// Per step per wave: 2 A-loads (issued FIRST -> counted vmcnt leaves DMAs in flight),
// 3 W-DMAs direct to LDS, f2b+2 ds_write for A, 8 ds_read + 12 MFMA. One barrier/step.
__global__ __launch_bounds__(256, 4) void qkv_proj_kernel(const float* __restrict__ emb,
                                                          const unsigned short* __restrict__ wt,
                                                          unsigned short* __restrict__ qkv) {
  __shared__ __align__(16) unsigned short Ab[2][32 * 64];   // 8 KB  (swizzled via staged writes)
  __shared__ __align__(16) unsigned short Wb[2][96 * 64];   // 24 KB (linear dest, src pre-swizzled)

  const int t    = threadIdx.x;
  const int wave = t >> 6;
  const int lane = t & 63;
  const int quad = lane >> 4;
  const int l16  = lane & 15;
  const int bx = blockIdx.x;
  const int rt = bx >> 1;          // row tile (32 rows)
  const int ch = bx & 1;           // col half (96 cols)
  const int wr = wave >> 1;        // row sub-tile (16 rows)
  const int wc = wave & 1;         // col sub (48 cols = 3 MFMA tiles)

  const float* aBase = emb + (size_t)rt * 32 * EMB;
  const char*  wChunk = (const char*)(wt + ch * 6144);   // + kb*24576 B per K-chunk

  // per-thread pre-swizzled W source byte offsets (3 DMA instrs per wave)
  int wsrc[3];
#pragma unroll
  for (int i = 0; i < 3; i++) {
    int u = (wave * 3 + i) * 64 + lane;     // 0..767 16B-units
    int row = u >> 3, k8 = u & 7;
    wsrc[i] = row * 128 + ((k8 ^ (row & 7)) << 4);
  }

  f32x4 acc[3];
#pragma unroll
  for (int j = 0; j < 3; j++) acc[j] = (f32x4){0.f, 0.f, 0.f, 0.f};
  f32x4 pa[2];

#define QKVA_ISSUE(kb)                                                              \
  do {                                                                              \
    _Pragma("unroll") for (int j = 0; j < 2; j++) {                                 \
      int u = t + j * 256;                                                          \
      pa[j] = *(const f32x4*)(aBase + (size_t)(u >> 4) * EMB + (kb) * 64 + (u & 15) * 4); \
    }                                                                               \
  } while (0)

#define QKVW_DMA(kb, buf)                                                           \
  do {                                                                              \
    _Pragma("unroll") for (int i = 0; i < 3; i++)                                   \
      GLOAD_LDS16(wChunk + (size_t)(kb) * 24576 + wsrc[i],                          \
                  (char*)&Wb[buf][0] + (wave * 3 + i) * 1024);                      \
  } while (0)

#define QKVA_STAGE(buf)                                                             \
  do {                                                                              \
    _Pragma("unroll") for (int j = 0; j < 2; j++) {                                 \
      int u = t + j * 256;                                                          \
      int row = u >> 4, kq = u & 15;                                                \
      unsigned int lo = (unsigned int)f2b(pa[j][0]) | ((unsigned int)f2b(pa[j][1]) << 16); \
      unsigned int hi = (unsigned int)f2b(pa[j][2]) | ((unsigned int)f2b(pa[j][3]) << 16); \
      uint2 pk; pk.x = lo; pk.y = hi;                                               \
      *(uint2*)((char*)&Ab[buf][0] + row * 128 + ((kq * 8) ^ ((row & 7) << 4))) = pk; \
    }                                                                               \
  } while (0)

#define QKV_COMPUTE(buf)                                                            \
  do {                                                                              \
    const int arow = wr * 16 + l16;                                                 \
    _Pragma("unroll") for (int kh = 0; kh < 2; kh++) {                              \
      bf16x8 af = *(const bf16x8*)((const char*)&Ab[buf][0] + arow * 128 +          \
                                   ((kh * 64 + quad * 16) ^ ((arow & 7) << 4)));    \
      _Pragma("unroll") for (int j = 0; j < 3; j++) {                               \
        const int coll = (wc * 3 + j) * 16 + l16;                                   \
        bf16x8 wf = *(const bf16x8*)((const char*)&Wb[buf][0] + coll * 128 +        \
                                     ((kh * 64 + quad * 16) ^ ((coll & 7) << 4)));  \
        acc[j] = __builtin_amdgcn_mfma_f32_16x16x32_bf16(af, wf, acc[j], 0, 0, 0);  \
      }                                                                             \
    }                                                                               \
  } while (0)

  // ---- prologue: A loads first (counted wait), then W DMA; stage A; barrier drains all
  QKVA_ISSUE(0);
  QKVW_DMA(0, 0);
  QKVA_STAGE(0);
  __syncthreads();

  // ---- main loop over 16 K-steps ----
  for (int kb = 0; kb < 16; kb++) {
    const int cur = kb & 1;
    const int nb  = cur ^ 1;
    if (kb < 15) {
      QKVA_ISSUE(kb + 1);        // oldest in queue -> A-stage waits vmcnt(3), DMAs stay in flight
      QKVW_DMA(kb + 1, nb);
    }
    QKV_COMPUTE(cur);
    if (kb < 15) QKVA_STAGE(nb);
    __syncthreads();             // drains DMA + ds writes for next step
  }

  // ---- epilogue: Q,K natural stores ----
#pragma unroll
  for (int j = 0; j < 3; j++) {
    int gc = ch * 96 + (wc * 3 + j) * 16 + l16;
    if (gc < 128) {                               // uniform per (wave,j)
      int m  = gc >> 6, cm = gc & 63;
#pragma unroll
      for (int r = 0; r < 4; r++) {
        int row = rt * 32 + wr * 16 + quad * 4 + r;   // C/D: row = quad*4+reg, col = l16
        qkv[(size_t)m * QKVSZ + (size_t)row * HD + cm] = f2b(acc[j][r]);
      }
    }
  }

  // ---- epilogue: V -> LDS transpose -> vT[b][h][s] coalesced store ----
  if (ch == 1) {
    __syncthreads();                               // LDS free after last MFMA
    unsigned short* Vsh = (unsigned short*)&Ab[0][0];   // 64 h x 40 pitch = 2560 shorts
#pragma unroll
    for (int j = 0; j < 3; j++) {
      int gc = 96 + (wc * 3 + j) * 16 + l16;
      if (gc >= 128) {
        int h = gc - 128;
#pragma unroll
        for (int r = 0; r < 4; r++)
          Vsh[h * 40 + wr * 16 + quad * 4 + r] = f2b(acc[j][r]);
      }
    }
    __syncthreads();
    int h  = t >> 2;
    int sq = (t & 3) * 8;
    int row0 = rt * 32;
    int b    = row0 >> 11;
    int seq0 = row0 & 2047;
    bf16x8 vv = *(const bf16x8*)(Vsh + h * 40 + sq);
    *(bf16x8*)(qkv + 2 * (size_t)QKVSZ + ((size_t)(b * 64 + h)) * SEQ + seq0 + sq) = vv;
  }
}

// ---------------- Flash attention: 4 waves/block, 64 q-rows, 4-tile split-K chunks --------
// K/V staged via global_load_lds (linear dest + pre-swizzled source); compute phase has
// ZERO vmcnt dependencies -- DMA issued at step top, drained by end-of-step barrier.
__global__ __launch_bounds__(256, 4) void attn_split(const unsigned short* __restrict__ qkv,
                                                     float* __restrict__ part,
                                                     float* __restrict__ out) {
  __shared__ __align__(16) unsigned short Kb[2][64 * 64];   // 2 x 8 KB
  __shared__ __align__(16) unsigned short Vb[2][64 * 64];   // 2 x 8 KB, Vt[h][key]
  __shared__ __align__(16) unsigned short Pb[4][16 * 64];   // per-wave P, swizzled

  const int t    = threadIdx.x;
  const int wave = t >> 6;
  const int lane = t & 63;
  const int quad = lane >> 4;
  const int l16  = lane & 15;
  const int B0 = blockIdx.x;        // 64-row q-block
  const int c  = blockIdx.y;        // chunk
  const int b  = blockIdx.z;
  const int nch = (B0 >> 2) + 1;
  if (c >= nch) return;
  const int t0 = c * 4;
  const int t1 = min(t0 + 3, B0);
  const int qt = B0 * 4 + wave;
  const int q0 = qt * 16;

  const unsigned short* qg = qkv;
  const unsigned short* kg = qkv + QKVSZ;
  const unsigned short* vg = qkv + 2 * QKVSZ;     // vT[b][h][s]

  const unsigned short* qptr = qg + ((size_t)(b * SEQ + q0 + l16)) * HD + quad * 8;
  const bf16x8 qf0 = *(const bf16x8*)qptr;        // d 0..31
  const bf16x8 qf1 = *(const bf16x8*)(qptr + 32); // d 32..63

  // DMA source offsets (2 instrs per wave per matrix); row = key (K) / head (V)
  int koff[2]; size_t voff[2];
#pragma unroll
  for (int i = 0; i < 2; i++) {
    int u = (wave * 2 + i) * 64 + lane;           // 0..511 16B-units
    int row = u >> 3, k8 = u & 7;
    int swz = (k8 ^ (row & 7)) << 4;
    koff[i] = row * 128 + swz;                          // + kb*8192 within batch plane
    voff[i] = ((size_t)(b * 64 + row) * SEQ) * 2 + swz; // + kb*128
  }
  const char* kgB = (const char*)kg + (size_t)b * SEQ * 128;
  const char* vgB = (const char*)vg;

  f32x4 o0 = {0,0,0,0}, o1 = {0,0,0,0}, o2 = {0,0,0,0}, o3 = {0,0,0,0};
  float mst[4] = {-INFINITY, -INFINITY, -INFINITY, -INFINITY};
  float lst[4] = {0.f, 0.f, 0.f, 0.f};
  const float sc = 0.125f * 1.44269504088896f;    // 1/sqrt(64) * log2(e)

  // prologue: DMA tile t0 -> buf0
#pragma unroll
  for (int i = 0; i < 2; i++) {
    GLOAD_LDS16(kgB + (size_t)t0 * 8192 + koff[i], (char*)&Kb[0][0] + (wave * 2 + i) * 1024);
    GLOAD_LDS16(vgB + voff[i] + (size_t)t0 * 128,  (char*)&Vb[0][0] + (wave * 2 + i) * 1024);
  }
  __syncthreads();

  for (int kb = t0; kb <= t1; kb++) {
    const int cur = (kb - t0) & 1;
    const int nb  = cur ^ 1;

    // issue next tile's DMA (in flight across the whole compute phase)
    if (kb < t1) {
#pragma unroll
      for (int i = 0; i < 2; i++) {
        GLOAD_LDS16(kgB + (size_t)(kb + 1) * 8192 + koff[i], (char*)&Kb[nb][0] + (wave * 2 + i) * 1024);
        GLOAD_LDS16(vgB + voff[i] + (size_t)(kb + 1) * 128,  (char*)&Vb[nb][0] + (wave * 2 + i) * 1024);
      }
    }

    // S = Q K^T  (4 ktiles of 16 keys)
    f32x4 s[4];
#pragma unroll
    for (int kt = 0; kt < 4; kt++) {
      int row = kt * 16 + l16;
      bf16x8 kf0 = *(const bf16x8*)((char*)&Kb[cur][0] + row * 128 + ((quad * 16) ^ ((row & 7) << 4)));
      bf16x8 kf1 = *(const bf16x8*)((char*)&Kb[cur][0] + row * 128 + ((64 + quad * 16) ^ ((row & 7) << 4)));
      f32x4 z = {0.f, 0.f, 0.f, 0.f};
      z = __builtin_amdgcn_mfma_f32_16x16x32_bf16(qf0, kf0, z, 0, 0, 0);
      z = __builtin_amdgcn_mfma_f32_16x16x32_bf16(qf1, kf1, z, 0, 0, 0);
      s[kt] = z;
    }

    // scale; causal mask only on the diagonal tile (kb == B0)
    if (kb == B0) {
#pragma unroll
      for (int r = 0; r < 4; r++) {
        int rowg = q0 + quad * 4 + r;
#pragma unroll
        for (int kt = 0; kt < 4; kt++) {
          int col = kb * 64 + kt * 16 + l16;
          float v = s[kt][r] * sc;
          s[kt][r] = (col > rowg) ? -INFINITY : v;
        }
      }
    } else {
#pragma unroll
      for (int r = 0; r < 4; r++)
#pragma unroll
        for (int kt = 0; kt < 4; kt++) s[kt][r] *= sc;
    }

    // online softmax (reduce across the 16-lane col group)
    float alpha[4];
#pragma unroll
    for (int r = 0; r < 4; r++) {
      float mx = fmaxf(fmaxf(s[0][r], s[1][r]), fmaxf(s[2][r], s[3][r]));
#pragma unroll
      for (int off = 1; off < 16; off <<= 1) mx = fmaxf(mx, __shfl_xor(mx, off, 64));
      float mnew = fmaxf(mst[r], mx);
      alpha[r] = exp2f(mst[r] - mnew);
      mst[r] = mnew;
    }
#pragma unroll
    for (int r = 0; r < 4; r++) {
      float sm = 0.f;
#pragma unroll
      for (int kt = 0; kt < 4; kt++) {
        float p = exp2f(s[kt][r] - mst[r]);
        s[kt][r] = p;
        sm += p;
      }
#pragma unroll
      for (int off = 1; off < 16; off <<= 1) sm += __shfl_xor(sm, off, 64);
      lst[r] = lst[r] * alpha[r] + sm;
    }
#pragma unroll
    for (int r = 0; r < 4; r++) { o0[r] *= alpha[r]; o1[r] *= alpha[r]; o2[r] *= alpha[r]; o3[r] *= alpha[r]; }

    // P (C-layout) -> per-wave LDS bf16 (swizzled); wave-local dep, no barrier needed
#pragma unroll
    for (int kt = 0; kt < 4; kt++)
#pragma unroll
      for (int r = 0; r < 4; r++) {
        int row = quad * 4 + r;
        *(unsigned short*)((char*)&Pb[wave][0] + row * 128 +
                           ((kt * 32 + l16 * 2) ^ ((row & 7) << 4))) = f2b(s[kt][r]);
      }

    // O += P V
#pragma unroll
    for (int kc = 0; kc < 2; kc++) {
      bf16x8 pf = *(const bf16x8*)((char*)&Pb[wave][0] + l16 * 128 +
                                   ((kc * 64 + quad * 16) ^ ((l16 & 7) << 4)));
      int r0 = l16, r1 = 16 + l16, r2 = 32 + l16, r3 = 48 + l16;
      bf16x8 vf0 = *(const bf16x8*)((char*)&Vb[cur][0] + r0 * 128 + ((kc * 64 + quad * 16) ^ ((r0 & 7) << 4)));
      bf16x8 vf1 = *(const bf16x8*)((char*)&Vb[cur][0] + r1 * 128 + ((kc * 64 + quad * 16) ^ ((r1 & 7) << 4)));
      bf16x8 vf2 = *(const bf16x8*)((char*)&Vb[cur][0] + r2 * 128 + ((kc * 64 + quad * 16) ^ ((r2 & 7) << 4)));
      bf16x8 vf3 = *(const bf16x8*)((char*)&Vb[cur][0] + r3 * 128 + ((kc * 64 + quad * 16) ^ ((r3 & 7) << 4)));
      o0 = __builtin_amdgcn_mfma_f32_16x16x32_bf16(pf, vf0, o0, 0, 0, 0);
      o1 = __builtin_amdgcn_mfma_f32_16x16x32_bf16(pf, vf1, o1, 0, 0, 0);
      o2 = __builtin_amdgcn_mfma_f32_16x16x32_bf16(pf, vf2, o2, 0, 0, 0);
      o3 = __builtin_amdgcn_mfma_f32_16x16x32_bf16(pf, vf3, o3, 0, 0, 0);
    }

    __syncthreads();   // drains next-tile DMA; buffers swap
  }

  if (nch == 1) {  // B0 < 4: single chunk, finalize directly
#pragma unroll
    for (int r = 0; r < 4; r++) {
      float inv = 1.f / lst[r];
      int rowg = q0 + quad * 4 + r;
      size_t ob = ((size_t)(b * SEQ + rowg)) * HD + l16;
      out[ob + 0]  = o0[r] * inv;
      out[ob + 16] = o1[r] * inv;
      out[ob + 32] = o2[r] * inv;
      out[ob + 48] = o3[r] * inv;
    }
  } else {         // write unnormalized partial + (m,l); row in [0,64) within qblock
    float* ps = part + ((size_t)((b * 32 + B0) * 8 + c)) * PSLOT2;
#pragma unroll
    for (int r = 0; r < 4; r++) {
      int row = wave * 16 + quad * 4 + r;
      ps[row * 64 + 0  + l16] = o0[r];
      ps[row * 64 + 16 + l16] = o1[r];
      ps[row * 64 + 32 + l16] = o2[r];
      ps[row * 64 + 48 + l16] = o3[r];
      if (l16 == 0) {
        ps[4096 + row] = mst[r];
        ps[4160 + row] = lst[r];
      }
    }
  }
}

// ---------------- merge nch partials per 64-row q-block ----------------
// grid (112, 8): bx = (B0-4)*4 + rg, B0 in [4,32), rg = row-group of 16.
// Fully unrolled 8-chunk accumulation with clamped addresses -> all loads in flight at once.
__global__ __launch_bounds__(256) void attn_merge(const float* __restrict__ part,
                                                  float* __restrict__ out) {
  const int bx = blockIdx.x;
  const int B0 = 4 + (bx >> 2);
  const int rg = bx & 3;
  const int b  = blockIdx.y;
  const int nch = (B0 >> 2) + 1;    // 2..8
  const int t  = threadIdx.x;
  const int h  = t & 63;
  const int rloc = t >> 6;          // 0..3
  const float* base = part + ((size_t)((b * 32 + B0) * 8)) * PSLOT2;
#pragma unroll
  for (int i = 0; i < 4; i++) {
    int row = rg * 16 + rloc * 4 + i;
    float mv[8], lv[8], ov[8];
#pragma unroll
    for (int cc = 0; cc < 8; cc++) {
      int cs = (cc < nch) ? cc : 0;                 // clamp: valid address, masked later
      const float* ps = base + (size_t)cs * PSLOT2;
      mv[cc] = ps[4096 + row];
      lv[cc] = ps[4160 + row];
      ov[cc] = ps[row * 64 + h];
    }
    float M = -INFINITY;
#pragma unroll
    for (int cc = 0; cc < 8; cc++) M = fmaxf(M, (cc < nch) ? mv[cc] : -INFINITY);
    float L = 0.f, o = 0.f;
#pragma unroll
    for (int cc = 0; cc < 8; cc++) {
      float e = (cc < nch) ? exp2f(mv[cc] - M) : 0.f;
      L += lv[cc] * e;
      o += ov[cc] * e;
    }
    out[((size_t)(b * SEQ + B0 * 64 + row)) * HD + h] = o / L;
  }
}

extern "C" void kernel_launch(void* const* d_in, const int* in_sizes, int n_in,
                              void* d_out, int out_size, void* d_ws, size_t ws_size,
                              hipStream_t stream) {
  const float* emb = (const float*)d_in[0];
  const float* wq  = (const float*)d_in[1];
  const float* wk  = (const float*)d_in[2];
  const float* wv  = (const float*)d_in[3];
  unsigned short* ws  = (unsigned short*)d_ws;
  unsigned short* wt  = ws;              // 196608 bf16
  unsigned short* qkv = ws + WTSZ;       // q,k natural + vT  (3 x 1048576 bf16)
  float* part = (float*)(ws + WTSZ + 3 * QKVSZ);   // 8*32*8 slots x 4224 fp32 = 34.6 MB

  hipLaunchKernelGGL(wtrans_kernel,   dim3(WTSZ / 256), dim3(256), 0, stream, wq, wk, wv, wt);
  hipLaunchKernelGGL(qkv_proj_kernel, dim3(1024),       dim3(256), 0, stream, emb, wt, qkv);
  hipLaunchKernelGGL(attn_split,      dim3(32, 8, 8),   dim3(256), 0, stream, qkv, part, (float*)d_out);
  hipLaunchKernelGGL(attn_merge,      dim3(112, 8),     dim3(256), 0, stream, part, (float*)d_out);
}

// Round 8
// 150.307 us; speedup vs baseline: 1.3906x; 1.0370x over previous
//
#include <hip/hip_runtime.h>

#define SEQ   2048
#define NBATCH 8
#define EMB   1024
#define HD    64
#define QKVSZ (NBATCH * SEQ * HD)   /* 1048576 elems per matrix */
#define WTSZ  (3 * HD * EMB)        /* 196608 */
#define PSLOT2 4224                 /* 64*64 O + 64 m + 64 l */

typedef __attribute__((ext_vector_type(8))) short bf16x8;
typedef __attribute__((ext_vector_type(4))) float f32x4;

__device__ inline unsigned short f2b(float f) {
  union { float f; unsigned int i; } u; u.f = f;
  unsigned int r = (u.i + 0x7FFFu + ((u.i >> 16) & 1u)) >> 16;  // RNE
  return (unsigned short)r;
}

// Direct global->LDS DMA, 16B per lane. LDS dest = uniform base + lane*16 (linear);
// swizzle is applied on the per-lane GLOBAL source address (inverse), read-side keeps XOR.
#define GLOAD_LDS16(g, l)                                              \
  __builtin_amdgcn_global_load_lds(                                    \
      (const __attribute__((address_space(1))) void*)(g),              \
      (__attribute__((address_space(3))) void*)(l), 16, 0, 0)

// ---------------- W transpose -> K-blocked layout [kb][m][c][kd] ----------------
__global__ __launch_bounds__(256) void wtrans_kernel(const float* __restrict__ wq,
                                                     const float* __restrict__ wk,
                                                     const float* __restrict__ wv,
                                                     unsigned short* __restrict__ wt) {
  int i = blockIdx.x * 256 + threadIdx.x;       // 0 .. 196607
  int kb  = i / 12288;
  int rem = i - kb * 12288;
  int m   = rem >> 12;          // 0..2
  int c   = (rem >> 6) & 63;    // output col within head
  int kd  = rem & 63;           // k within block
  const float* src = (m == 0) ? wq : ((m == 1) ? wk : wv);
  int d = kb * 64 + kd;
  wt[i] = f2b(src[d * 64 + c]);
}

// ---------------- QKV projection: W via global_load_lds, A reg-staged ----------------
// XCD-pair swizzle: col-half pair (rt,0)/(rt,1) = blocks bx and bx^8 -> same bx%8 ->
// same XCD, co-resident -> the shared 32 A-rows are fetched from HBM once, second
// reader hits that XCD's L2. (Old bx=rt*2+ch put pairs on DIFFERENT XCDs: A read 2x.)
__global__ __launch_bounds__(256, 4) void qkv_proj_kernel(const float* __restrict__ emb,
                                                          const unsigned short* __restrict__ wt,
                                                          unsigned short* __restrict__ qkv) {
  __shared__ __align__(16) unsigned short Ab[2][32 * 64];   // 8 KB  (swizzled via staged writes)
  __shared__ __align__(16) unsigned short Wb[2][96 * 64];   // 24 KB (linear dest, src pre-swizzled)

  const int t    = threadIdx.x;
  const int wave = t >> 6;
  const int lane = t & 63;
  const int quad = lane >> 4;
  const int l16  = lane & 15;
  const int bx = blockIdx.x;
  const int rt = ((bx >> 4) << 3) | (bx & 7);   // row tile (32 rows)
  const int ch = (bx >> 3) & 1;                 // col half (96 cols)
  const int wr = wave >> 1;        // row sub-tile (16 rows)
  const int wc = wave & 1;         // col sub (48 cols = 3 MFMA tiles)

  const float* aBase = emb + (size_t)rt * 32 * EMB;
  const char*  wChunk = (const char*)(wt + ch * 6144);   // + kb*24576 B per K-chunk

  // per-thread pre-swizzled W source byte offsets (3 DMA instrs per wave)
  int wsrc[3];
#pragma unroll
  for (int i = 0; i < 3; i++) {
    int u = (wave * 3 + i) * 64 + lane;     // 0..767 16B-units
    int row = u >> 3, k8 = u & 7;
    wsrc[i] = row * 128 + ((k8 ^ (row & 7)) << 4);
  }

  f32x4 acc[3];
#pragma unroll
  for (int j = 0; j < 3; j++) acc[j] = (f32x4){0.f, 0.f, 0.f, 0.f};
  f32x4 pa[2];

#define QKVA_ISSUE(kb)                                                              \
  do {                                                                              \
    _Pragma("unroll") for (int j = 0; j < 2; j++) {                                 \
      int u = t + j * 256;                                                          \
      pa[j] = *(const f32x4*)(aBase + (size_t)(u >> 4) * EMB + (kb) * 64 + (u & 15) * 4); \
    }                                                                               \
  } while (0)

#define QKVW_DMA(kb, buf)                                                           \
  do {                                                                              \
    _Pragma("unroll") for (int i = 0; i < 3; i++)                                   \
      GLOAD_LDS16(wChunk + (size_t)(kb) * 24576 + wsrc[i],                          \
                  (char*)&Wb[buf][0] + (wave * 3 + i) * 1024);                      \
  } while (0)

#define QKVA_STAGE(buf)                                                             \
  do {                                                                              \
    _Pragma("unroll") for (int j = 0; j < 2; j++) {                                 \
      int u = t + j * 256;                                                          \
      int row = u >> 4, kq = u & 15;                                                \
      unsigned int lo = (unsigned int)f2b(pa[j][0]) | ((unsigned int)f2b(pa[j][1]) << 16); \
      unsigned int hi = (unsigned int)f2b(pa[j][2]) | ((unsigned int)f2b(pa[j][3]) << 16); \
      uint2 pk; pk.x = lo; pk.y = hi;                                               \
      *(uint2*)((char*)&Ab[buf][0] + row * 128 + ((kq * 8) ^ ((row & 7) << 4))) = pk; \
    }                                                                               \
  } while (0)

#define QKV_COMPUTE(buf)                                                            \
  do {                                                                              \
    const int arow = wr * 16 + l16;                                                 \
    _Pragma("unroll") for (int kh = 0; kh < 2; kh++) {                              \
      bf16x8 af = *(const bf16x8*)((const char*)&Ab[buf][0] + arow * 128 +          \
                                   ((kh * 64 + quad * 16) ^ ((arow & 7) << 4)));    \
      _Pragma("unroll") for (int j = 0; j < 3; j++) {                               \
        const int coll = (wc * 3 + j) * 16 + l16;                                   \
        bf16x8 wf = *(const bf16x8*)((const char*)&Wb[buf][0] + coll * 128 +        \
                                     ((kh * 64 + quad * 16) ^ ((coll & 7) << 4)));  \
        acc[j] = __builtin_amdgcn_mfma_f32_16x16x32_bf16(af, wf, acc[j], 0, 0, 0);  \
      }                                                                             \
    }                                                                               \
  } while (0)

  // ---- prologue: A loads first (counted wait), then W DMA; stage A; barrier drains all
  QKVA_ISSUE(0);
  QKVW_DMA(0, 0);
  QKVA_STAGE(0);
  __syncthreads();

  // ---- main loop over 16 K-steps ----
  for (int kb = 0; kb < 16; kb++) {
    const int cur = kb & 1;
    const int nb  = cur ^ 1;
    if (kb < 15) {
      QKVA_ISSUE(kb + 1);        // oldest in queue -> A-stage waits vmcnt(3), DMAs stay in flight
      QKVW_DMA(kb + 1, nb);
    }
    QKV_COMPUTE(cur);
    if (kb < 15) QKVA_STAGE(nb);
    __syncthreads();             // drains DMA + ds writes for next step
  }

  // ---- epilogue: Q,K natural stores ----
#pragma unroll
  for (int j = 0; j < 3; j++) {
    int gc = ch * 96 + (wc * 3 + j) * 16 + l16;
    if (gc < 128) {                               // uniform per (wave,j)
      int m  = gc >> 6, cm = gc & 63;
#pragma unroll
      for (int r = 0; r < 4; r++) {
        int row = rt * 32 + wr * 16 + quad * 4 + r;   // C/D: row = quad*4+reg, col = l16
        qkv[(size_t)m * QKVSZ + (size_t)row * HD + cm] = f2b(acc[j][r]);
      }
    }
  }

  // ---- epilogue: V -> LDS transpose -> vT[b][h][s] coalesced store ----
  if (ch == 1) {
    __syncthreads();                               // LDS free after last MFMA
    unsigned short* Vsh = (unsigned short*)&Ab[0][0];   // 64 h x 40 pitch = 2560 shorts
#pragma unroll
    for (int j = 0; j < 3; j++) {
      int gc = 96 + (wc * 3 + j) * 16 + l16;
      if (gc >= 128) {
        int h = gc - 128;
#pragma unroll
        for (int r = 0; r < 4; r++)
          Vsh[h * 40 + wr * 16 + quad * 4 + r] = f2b(acc[j][r]);
      }
    }
    __syncthreads();
    int h  = t >> 2;
    int sq = (t & 3) * 8;
    int row0 = rt * 32;
    int b    = row0 >> 11;
    int seq0 = row0 & 2047;
    bf16x8 vv = *(const bf16x8*)(Vsh + h * 40 + sq);
    *(bf16x8*)(qkv + 2 * (size_t)QKVSZ + ((size_t)(b * 64 + h)) * SEQ + seq0 + sq) = vv;
  }
}

// ---------------- Flash attention: 4 waves/block, 64 q-rows, 8-tile split-K chunks --------
// grid = (32 qblocks, 4 chunks, 8 batch). Block (B0,c) covers k-tiles [8c, min(8c+7,B0)];
// B0 < 8 has a single chunk -> finalized directly (no partials). Partial traffic halved vs
// 4-tile chunks; 640 active blocks x 4 waves = ~10 waves/CU.
__global__ __launch_bounds__(256, 4) void attn_split(const unsigned short* __restrict__ qkv,
                                                     float* __restrict__ part,
                                                     float* __restrict__ out) {
  __shared__ __align__(16) unsigned short Kb[2][64 * 64];   // 2 x 8 KB
  __shared__ __align__(16) unsigned short Vb[2][64 * 64];   // 2 x 8 KB, Vt[h][key]
  __shared__ __align__(16) unsigned short Pb[4][16 * 64];   // per-wave P, swizzled

  const int t    = threadIdx.x;
  const int wave = t >> 6;
  const int lane = t & 63;
  const int quad = lane >> 4;
  const int l16  = lane & 15;
  const int B0 = blockIdx.x;        // 64-row q-block
  const int c  = blockIdx.y;        // chunk (8 tiles each)
  const int b  = blockIdx.z;
  const int nch = (B0 >> 3) + 1;    // 1..4
  if (c >= nch) return;
  const int t0 = c * 8;
  const int t1 = min(t0 + 7, B0);
  const int qt = B0 * 4 + wave;
  const int q0 = qt * 16;

  const unsigned short* qg = qkv;
  const unsigned short* kg = qkv + QKVSZ;
  const unsigned short* vg = qkv + 2 * QKVSZ;     // vT[b][h][s]

  const unsigned short* qptr = qg + ((size_t)(b * SEQ + q0 + l16)) * HD + quad * 8;
  const bf16x8 qf0 = *(const bf16x8*)qptr;        // d 0..31
  const bf16x8 qf1 = *(const bf16x8*)(qptr + 32); // d 32..63

  // DMA source offsets (2 instrs per wave per matrix); row = key (K) / head (V)
  int koff[2]; size_t voff[2];
#pragma unroll
  for (int i = 0; i < 2; i++) {
    int u = (wave * 2 + i) * 64 + lane;           // 0..511 16B-units
    int row = u >> 3, k8 = u & 7;
    int swz = (k8 ^ (row & 7)) << 4;
    koff[i] = row * 128 + swz;                          // + kb*8192 within batch plane
    voff[i] = ((size_t)(b * 64 + row) * SEQ) * 2 + swz; // + kb*128
  }
  const char* kgB = (const char*)kg + (size_t)b * SEQ * 128;
  const char* vgB = (const char*)vg;

  f32x4 o0 = {0,0,0,0}, o1 = {0,0,0,0}, o2 = {0,0,0,0}, o3 = {0,0,0,0};
  float mst[4] = {-INFINITY, -INFINITY, -INFINITY, -INFINITY};
  float lst[4] = {0.f, 0.f, 0.f, 0.f};
  const float sc = 0.125f * 1.44269504088896f;    // 1/sqrt(64) * log2(e)

  // prologue: DMA tile t0 -> buf0
#pragma unroll
  for (int i = 0; i < 2; i++) {
    GLOAD_LDS16(kgB + (size_t)t0 * 8192 + koff[i], (char*)&Kb[0][0] + (wave * 2 + i) * 1024);
    GLOAD_LDS16(vgB + voff[i] + (size_t)t0 * 128,  (char*)&Vb[0][0] + (wave * 2 + i) * 1024);
  }
  __syncthreads();

  for (int kb = t0; kb <= t1; kb++) {
    const int cur = (kb - t0) & 1;
    const int nb  = cur ^ 1;

    // issue next tile's DMA (in flight across the whole compute phase)
    if (kb < t1) {
#pragma unroll
      for (int i = 0; i < 2; i++) {
        GLOAD_LDS16(kgB + (size_t)(kb + 1) * 8192 + koff[i], (char*)&Kb[nb][0] + (wave * 2 + i) * 1024);
        GLOAD_LDS16(vgB + voff[i] + (size_t)(kb + 1) * 128,  (char*)&Vb[nb][0] + (wave * 2 + i) * 1024);
      }
    }

    // S = Q K^T  (4 ktiles of 16 keys)
    f32x4 s[4];
#pragma unroll
    for (int kt = 0; kt < 4; kt++) {
      int row = kt * 16 + l16;
      bf16x8 kf0 = *(const bf16x8*)((char*)&Kb[cur][0] + row * 128 + ((quad * 16) ^ ((row & 7) << 4)));
      bf16x8 kf1 = *(const bf16x8*)((char*)&Kb[cur][0] + row * 128 + ((64 + quad * 16) ^ ((row & 7) << 4)));
      f32x4 z = {0.f, 0.f, 0.f, 0.f};
      z = __builtin_amdgcn_mfma_f32_16x16x32_bf16(qf0, kf0, z, 0, 0, 0);
      z = __builtin_amdgcn_mfma_f32_16x16x32_bf16(qf1, kf1, z, 0, 0, 0);
      s[kt] = z;
    }

    // scale; causal mask only on the diagonal tile (kb == B0)
    if (kb == B0) {
#pragma unroll
      for (int r = 0; r < 4; r++) {
        int rowg = q0 + quad * 4 + r;
#pragma unroll
        for (int kt = 0; kt < 4; kt++) {
          int col = kb * 64 + kt * 16 + l16;
          float v = s[kt][r] * sc;
          s[kt][r] = (col > rowg) ? -INFINITY : v;
        }
      }
    } else {
#pragma unroll
      for (int r = 0; r < 4; r++)
#pragma unroll
        for (int kt = 0; kt < 4; kt++) s[kt][r] *= sc;
    }

    // online softmax (reduce across the 16-lane col group)
    float alpha[4];
#pragma unroll
    for (int r = 0; r < 4; r++) {
      float mx = fmaxf(fmaxf(s[0][r], s[1][r]), fmaxf(s[2][r], s[3][r]));
#pragma unroll
      for (int off = 1; off < 16; off <<= 1) mx = fmaxf(mx, __shfl_xor(mx, off, 64));
      float mnew = fmaxf(mst[r], mx);
      alpha[r] = exp2f(mst[r] - mnew);
      mst[r] = mnew;
    }
#pragma unroll
    for (int r = 0; r < 4; r++) {
      float sm = 0.f;
#pragma unroll
      for (int kt = 0; kt < 4; kt++) {
        float p = exp2f(s[kt][r] - mst[r]);
        s[kt][r] = p;
        sm += p;
      }
#pragma unroll
      for (int off = 1; off < 16; off <<= 1) sm += __shfl_xor(sm, off, 64);
      lst[r] = lst[r] * alpha[r] + sm;
    }
#pragma unroll
    for (int r = 0; r < 4; r++) { o0[r] *= alpha[r]; o1[r] *= alpha[r]; o2[r] *= alpha[r]; o3[r] *= alpha[r]; }

    // P (C-layout) -> per-wave LDS bf16 (swizzled); wave-local dep, no barrier needed
#pragma unroll
    for (int kt = 0; kt < 4; kt++)
#pragma unroll
      for (int r = 0; r < 4; r++) {
        int row = quad * 4 + r;
        *(unsigned short*)((char*)&Pb[wave][0] + row * 128 +
                           ((kt * 32 + l16 * 2) ^ ((row & 7) << 4))) = f2b(s[kt][r]);
      }

    // O += P V
#pragma unroll
    for (int kc = 0; kc < 2; kc++) {
      bf16x8 pf = *(const bf16x8*)((char*)&Pb[wave][0] + l16 * 128 +
                                   ((kc * 64 + quad * 16) ^ ((l16 & 7) << 4)));
      int r0 = l16, r1 = 16 + l16, r2 = 32 + l16, r3 = 48 + l16;
      bf16x8 vf0 = *(const bf16x8*)((char*)&Vb[cur][0] + r0 * 128 + ((kc * 64 + quad * 16) ^ ((r0 & 7) << 4)));
      bf16x8 vf1 = *(const bf16x8*)((char*)&Vb[cur][0] + r1 * 128 + ((kc * 64 + quad * 16) ^ ((r1 & 7) << 4)));
      bf16x8 vf2 = *(const bf16x8*)((char*)&Vb[cur][0] + r2 * 128 + ((kc * 64 + quad * 16) ^ ((r2 & 7) << 4)));
      bf16x8 vf3 = *(const bf16x8*)((char*)&Vb[cur][0] + r3 * 128 + ((kc * 64 + quad * 16) ^ ((r3 & 7) << 4)));
      o0 = __builtin_amdgcn_mfma_f32_16x16x32_bf16(pf, vf0, o0, 0, 0, 0);
      o1 = __builtin_amdgcn_mfma_f32_16x16x32_bf16(pf, vf1, o1, 0, 0, 0);
      o2 = __builtin_amdgcn_mfma_f32_16x16x32_bf16(pf, vf2, o2, 0, 0, 0);
      o3 = __builtin_amdgcn_mfma_f32_16x16x32_bf16(pf, vf3, o3, 0, 0, 0);
    }

    __syncthreads();   // drains next-tile DMA; buffers swap
  }

  if (nch == 1) {  // B0 < 8: single chunk, finalize directly
#pragma unroll
    for (int r = 0; r < 4; r++) {
      float inv = 1.f / lst[r];
      int rowg = q0 + quad * 4 + r;
      size_t ob = ((size_t)(b * SEQ + rowg)) * HD + l16;
      out[ob + 0]  = o0[r] * inv;
      out[ob + 16] = o1[r] * inv;
      out[ob + 32] = o2[r] * inv;
      out[ob + 48] = o3[r] * inv;
    }
  } else {         // write unnormalized partial + (m,l); row in [0,64) within qblock
    float* ps = part + ((size_t)((b * 32 + B0) * 4 + c)) * PSLOT2;
#pragma unroll
    for (int r = 0; r < 4; r++) {
      int row = wave * 16 + quad * 4 + r;
      ps[row * 64 + 0  + l16] = o0[r];
      ps[row * 64 + 16 + l16] = o1[r];
      ps[row * 64 + 32 + l16] = o2[r];
      ps[row * 64 + 48 + l16] = o3[r];
      if (l16 == 0) {
        ps[4096 + row] = mst[r];
        ps[4160 + row] = lst[r];
      }
    }
  }
}

// ---------------- merge nch partials per 64-row q-block ----------------
// grid (96, 8): bx = (B0-8)*4 + rg, B0 in [8,32), rg = row-group of 16.
// Fully unrolled 4-chunk accumulation with clamped addresses -> all loads in flight at once.
__global__ __launch_bounds__(256) void attn_merge(const float* __restrict__ part,
                                                  float* __restrict__ out) {
  const int bx = blockIdx.x;
  const int B0 = 8 + (bx >> 2);
  const int rg = bx & 3;
  const int b  = blockIdx.y;
  const int nch = (B0 >> 3) + 1;    // 2..4
  const int t  = threadIdx.x;
  const int h  = t & 63;
  const int rloc = t >> 6;          // 0..3
  const float* base = part + ((size_t)((b * 32 + B0) * 4)) * PSLOT2;
#pragma unroll
  for (int i = 0; i < 4; i++) {
    int row = rg * 16 + rloc * 4 + i;
    float mv[4], lv[4], ov[4];
#pragma unroll
    for (int cc = 0; cc < 4; cc++) {
      int cs = (cc < nch) ? cc : 0;                 // clamp: valid address, masked later
      const float* ps = base + (size_t)cs * PSLOT2;
      mv[cc] = ps[4096 + row];
      lv[cc] = ps[4160 + row];
      ov[cc] = ps[row * 64 + h];
    }
    float M = -INFINITY;
#pragma unroll
    for (int cc = 0; cc < 4; cc++) M = fmaxf(M, (cc < nch) ? mv[cc] : -INFINITY);
    float L = 0.f, o = 0.f;
#pragma unroll
    for (int cc = 0; cc < 4; cc++) {
      float e = (cc < nch) ? exp2f(mv[cc] - M) : 0.f;
      L += lv[cc] * e;
      o += ov[cc] * e;
    }
    out[((size_t)(b * SEQ + B0 * 64 + row)) * HD + h] = o / L;
  }
}

extern "C" void kernel_launch(void* const* d_in, const int* in_sizes, int n_in,
                              void* d_out, int out_size, void* d_ws, size_t ws_size,
                              hipStream_t stream) {
  const float* emb = (const float*)d_in[0];
  const float* wq  = (const float*)d_in[1];
  const float* wk  = (const float*)d_in[2];
  const float* wv  = (const float*)d_in[3];
  unsigned short* ws  = (unsigned short*)d_ws;
  unsigned short* wt  = ws;              // 196608 bf16
  unsigned short* qkv = ws + WTSZ;       // q,k natural + vT  (3 x 1048576 bf16)
  float* part = (float*)(ws + WTSZ + 3 * QKVSZ);   // 32*4*8 slots x 4224 fp32 = 17.3 MB

  hipLaunchKernelGGL(wtrans_kernel,   dim3(WTSZ / 256), dim3(256), 0, stream, wq, wk, wv, wt);
  hipLaunchKernelGGL(qkv_proj_kernel, dim3(1024),       dim3(256), 0, stream, emb, wt, qkv);
  hipLaunchKernelGGL(attn_split,      dim3(32, 4, 8),   dim3(256), 0, stream, qkv, part, (float*)d_out);
  hipLaunchKernelGGL(attn_merge,      dim3(96, 8),      dim3(256), 0, stream, part, (float*)d_out);
}